// Round 7
// baseline (396.936 us; speedup 1.0000x reference)
//
#include <hip/hip_runtime.h>

#define SQ 2048
#define HD 1024
#define NB 8
#define NTOT (NB*SQ)
#define NT2 8           // SQ/256
#define NTRI2 36        // NT2*(NT2+1)/2
#define CE ((long long)NTRI2*65536)  // compact score elems per batch (256x256 tiles)

typedef _Float16 f16x8 __attribute__((ext_vector_type(8)));
typedef float f32x4 __attribute__((ext_vector_type(4)));
typedef short s16x8 __attribute__((ext_vector_type(8)));
typedef unsigned short u16;

__device__ __forceinline__ u16 f2h(float x){
  _Float16 h = (_Float16)x;
  u16 u; __builtin_memcpy(&u, &h, 2); return u;
}

// async global->LDS: dest is wave-uniform base, HW adds lane*16
#define STG(gp, lp) __builtin_amdgcn_global_load_lds( \
    (const __attribute__((address_space(1))) unsigned*)(gp), \
    (__attribute__((address_space(3))) unsigned*)(lp), 16, 0, 0)

// ---------------------------------------------------------------------------
// 256x256 f16 MFMA GEMM, BK=32, 8 waves (2M x 4N), wave tile 128x64.
// DEEP PIPELINE (T3+T4): 4-buffer LDS ring (4 x 32KB), tile kt+3 staged at
// top of iter kt -> 3 tiles in flight; iter-bottom wait is COUNTED
// s_waitcnt vmcnt(8) (=4 loads/tile x 2 tiles still flying), never 0 except
// the tail. Raw s_barrier only. LDS tile layout: 128 lines x 128B; line r',
// logical granule q' (q'=(row>>7)*4+kq) stored at q'^(r'&7) -> ds_read_b128
// fragments 2-way max (free); staging source pre-inverse-swizzled.
// EPI 0: QKV. z=0:Q->f16, z=1:K->f16, z=2:V->fp32(d_out) + Vt f16[H,S]
// EPI 1: scores -> fp32 compact triangular 256^2 tiles (t = tri index)
// EPI 2: PV + residual; A = compact P tiles; K trimmed to (bi+1)*256
// ---------------------------------------------------------------------------
template<int EPI>
__global__ __launch_bounds__(512, 2)
void gemm8(const u16* __restrict__ A, const u16* __restrict__ B,
           float* Cf, u16* Ch, u16* Vt,
           const float* __restrict__ b0, const float* __restrict__ b1,
           const float* __restrict__ b2,
           int K, int lda, int ldb, int ldc,
           long long sA, long long sB, long long sC)
{
  const int z = blockIdx.z;
  int bi, bj, tri = 0;
  if (EPI == 1){                       // triangular decode: t -> (i, j<=i)
    int t = blockIdx.x;
    int i = (int)((sqrtf(8.f * (float)t + 1.f) - 1.f) * 0.5f);
    while ((i + 1) * (i + 2) / 2 <= t) ++i;
    while (i * (i + 1) / 2 > t) --i;
    bi = i;  bj = t - i * (i + 1) / 2;  tri = t;
  } else {
    bi = blockIdx.x;  bj = blockIdx.y;
    if (EPI == 2) tri = bi * (bi + 1) / 2;
  }

  __shared__ short lds[4 * 16384];     // 4 ring bufs x (A 16KB + B 16KB)

  const int tid  = threadIdx.x;
  const int lane = tid & 63, w = tid >> 6;
  const int wm2 = w >> 2, wn4 = w & 3;
  const int lrow = lane & 15, kgrp = lane >> 4;

  const long long rowA = (long long)bi * 256;
  const long long colB = (long long)bj * 256;

  // ---- staging sources: 2 insts per operand, 16B/lane, pre-inverse-swizzled
  const int rt = tid >> 3;                     // 0..63
  const int qp = (tid & 7) ^ (rt & 7);         // logical granule q' (0..7)
  const int kq = qp & 3;                       // k-quad within tile
  const int rh = (qp >> 2) << 7;               // +128 rows if q' >= 4

  const u16 *sAp[2], *sBp[2];
  if (EPI == 2){
    const u16* Pb = A + (long long)z * sA + (long long)tri * 65536;
    #pragma unroll
    for (int i = 0; i < 2; i++)
      sAp[i] = Pb + (i * 64 + rt + rh) * 256 + kq * 8;
  } else {
    const u16* Ab = A + (EPI == 0 ? 0LL : (long long)z * sA);
    #pragma unroll
    for (int i = 0; i < 2; i++)
      sAp[i] = Ab + (rowA + i * 64 + rt + rh) * (long long)lda + kq * 8;
  }
  {
    const u16* Bb = B + (long long)z * sB;
    #pragma unroll
    for (int i = 0; i < 2; i++)
      sBp[i] = Bb + (colB + i * 64 + rt + rh) * (long long)ldb + kq * 8;
  }

  // ---- fragment read offsets (shorts, within ring buffer) ----
  const int aoff = lrow * 64 + ((((wm2 << 2) | kgrp) ^ (lrow & 7)) << 3);               // + m*1024
  const int boff = 8192 + ((wn4 & 1) * 64 + lrow) * 64
                 + (((((wn4 >> 1) << 2) | kgrp) ^ (lrow & 7)) << 3);                    // + n*1024

  f32x4 acc[8][4];
  const f32x4 zf = {0.f, 0.f, 0.f, 0.f};
  #pragma unroll
  for (int m = 0; m < 8; m++)
    #pragma unroll
    for (int n = 0; n < 4; n++) acc[m][n] = zf;

  int KT = K >> 5;
  if (EPI == 2){ int t = (bi + 1) * 8; if (t < KT) KT = t; }

  auto stage = [&](int b){
    #pragma unroll
    for (int i = 0; i < 2; i++) STG(sAp[i], lds + b * 16384 +        (i * 8 + w) * 512);
    #pragma unroll
    for (int i = 0; i < 2; i++) STG(sBp[i], lds + b * 16384 + 8192 + (i * 8 + w) * 512);
  };
  auto advance = [&](int tS){
    long long advA = 32;
    if (EPI == 2) advA = ((tS & 7) == 7) ? (65536 - 224) : 32;
    sAp[0] += advA; sAp[1] += advA; sBp[0] += 32; sBp[1] += 32;
  };

  // prologue: stage up to 3 tiles into bufs 0,1,2
  stage(0); advance(0);
  if (KT > 1){ stage(1); advance(1); }
  if (KT > 2){ stage(2); advance(2); }
  if (KT > 2)      { asm volatile("s_waitcnt vmcnt(8)" ::: "memory"); }
  else if (KT > 1) { asm volatile("s_waitcnt vmcnt(4)" ::: "memory"); }
  else             { asm volatile("s_waitcnt vmcnt(0)" ::: "memory"); }
  __builtin_amdgcn_s_barrier();

  for (int kt = 0; kt < KT; ++kt){
    const short* Ab = lds + (kt & 3) * 16384;
    if (kt + 3 < KT){ stage((kt + 3) & 3); advance(kt + 3); }

    f16x8 bfr[4], af[4];
    #pragma unroll
    for (int n = 0; n < 4; n++)
      bfr[n] = *(const f16x8*)(Ab + boff + n * 1024);
    #pragma unroll
    for (int m = 0; m < 4; m++)
      af[m] = *(const f16x8*)(Ab + aoff + m * 1024);

    __builtin_amdgcn_s_setprio(1);
    #pragma unroll
    for (int n = 0; n < 4; n++)
      #pragma unroll
      for (int m = 0; m < 4; m++)
        acc[m][n] = __builtin_amdgcn_mfma_f32_16x16x32_f16(af[m], bfr[n], acc[m][n], 0, 0, 0);
    __builtin_amdgcn_s_setprio(0);
    __builtin_amdgcn_s_barrier();            // phase barrier (scheduling only)

    #pragma unroll
    for (int m = 0; m < 4; m++)
      af[m] = *(const f16x8*)(Ab + aoff + (4 + m) * 1024);

    __builtin_amdgcn_s_setprio(1);
    #pragma unroll
    for (int n = 0; n < 4; n++)
      #pragma unroll
      for (int m = 0; m < 4; m++)
        acc[4 + m][n] = __builtin_amdgcn_mfma_f32_16x16x32_f16(af[m], bfr[n], acc[4 + m][n], 0, 0, 0);
    __builtin_amdgcn_s_setprio(0);

    const int rem = KT - 1 - kt;
    if (rem >= 3)      { asm volatile("s_waitcnt vmcnt(8)" ::: "memory"); }
    else if (rem == 2) { asm volatile("s_waitcnt vmcnt(4)" ::: "memory"); }
    else if (rem == 1) { asm volatile("s_waitcnt vmcnt(0)" ::: "memory"); }
    if (rem > 0) __builtin_amdgcn_s_barrier();
  }

  // ---- epilogues ----
  if (EPI == 0){
    if (z < 2){
      u16* c = Ch + (long long)z * sC;
      const float* bias = z ? b1 : b0;
      #pragma unroll
      for (int n = 0; n < 4; n++){
        int col = (int)colB + wn4 * 64 + n * 16 + lrow;
        float ba = bias[col];
        #pragma unroll
        for (int m = 0; m < 8; m++){
          long long r = rowA + wm2 * 128 + m * 16 + kgrp * 4;
          #pragma unroll
          for (int j = 0; j < 4; j++)
            c[(r + j) * ldc + col] = f2h(acc[m][n][j] + ba);
        }
      }
    } else {
      #pragma unroll
      for (int n = 0; n < 4; n++){
        int col = (int)colB + wn4 * 64 + n * 16 + lrow;
        float ba = b2[col];
        #pragma unroll
        for (int m = 0; m < 8; m++){
          long long r = rowA + wm2 * 128 + m * 16 + kgrp * 4;
          int bb = (int)(r >> 11);
          int s  = (int)(r & 2047);
          u16* vtc = Vt + ((long long)bb * HD + col) * SQ + s;
          #pragma unroll
          for (int j = 0; j < 4; j++){
            float v = acc[m][n][j] + ba;
            Cf[(r + j) * ldc + col] = v;
            vtc[j] = f2h(v);
          }
        }
      }
    }
  } else if (EPI == 1){
    // compact 256x256 tile store, ld=256
    float* cf = Cf + (long long)z * sC + (long long)tri * 65536;
    #pragma unroll
    for (int n = 0; n < 4; n++){
      int col = wn4 * 64 + n * 16 + lrow;
      #pragma unroll
      for (int m = 0; m < 8; m++){
        int r = wm2 * 128 + m * 16 + kgrp * 4;
        #pragma unroll
        for (int j = 0; j < 4; j++)
          cf[(r + j) * 256 + col] = acc[m][n][j];
      }
    }
  } else {
    float* cf = Cf + (long long)z * sC;
    #pragma unroll
    for (int n = 0; n < 4; n++){
      int col = (int)colB + wn4 * 64 + n * 16 + lrow;
      #pragma unroll
      for (int m = 0; m < 8; m++){
        long long r = rowA + wm2 * 128 + m * 16 + kgrp * 4;
        #pragma unroll
        for (int j = 0; j < 4; j++){
          long long o = (r + j) * ldc + col;
          cf[o] = acc[m][n][j] + cf[o];     // residual: read V then overwrite
        }
      }
    }
  }
}

// x fp32 -> f16 plane
__global__ __launch_bounds__(256)
void prep_x(const float* __restrict__ X, u16* __restrict__ Xh)
{
  const long long n8 = (long long)NTOT * HD / 8;
  for (long long i = (long long)blockIdx.x * 256 + threadIdx.x; i < n8;
       i += (long long)gridDim.x * 256){
    const float* p = X + i * 8;
    float4 a = *(const float4*)p;
    float4 b = *(const float4*)(p + 4);
    float f[8] = {a.x, a.y, a.z, a.w, b.x, b.y, b.z, b.w};
    s16x8 h;
    #pragma unroll
    for (int j = 0; j < 8; j++) h[j] = (short)f2h(f[j]);
    *(s16x8*)&Xh[i * 8] = h;
  }
}

// W[k][n] -> transposed f16 Wt[z][n][k]
__global__ void prep_w(const float* __restrict__ Wq, const float* __restrict__ Wk,
                       const float* __restrict__ Wv, u16* __restrict__ Wt)
{
  __shared__ float t[32][33];
  const float* Win = (blockIdx.z == 0) ? Wq : (blockIdx.z == 1) ? Wk : Wv;
  const size_t zo = (size_t)blockIdx.z * HD * HD;
  int n0 = blockIdx.x * 32, k0 = blockIdx.y * 32;
  int tx = threadIdx.x, ty = threadIdx.y;
  #pragma unroll
  for (int i = 0; i < 4; i++)
    t[ty + 8*i][tx] = Win[(size_t)(k0 + ty + 8*i) * HD + n0 + tx];
  __syncthreads();
  #pragma unroll
  for (int i = 0; i < 4; i++)
    Wt[zo + (size_t)(n0 + ty + 8*i) * HD + k0 + tx] = f2h(t[tx][ty + 8*i]);
}

// softmax over compact triangular SC (256^2 tiles) -> compact P (f16)
__global__ __launch_bounds__(256)
void softmax_causal(const float* __restrict__ SC, u16* __restrict__ P)
{
  const int s = blockIdx.x;
  const int i = s >> 8;                 // 256-row tile
  const int tri = i * (i + 1) / 2;
  const long long base = (long long)blockIdx.y * CE + (long long)tri * 65536
                       + (long long)(s & 255) * 256;
  const float* scb = SC + base;
  u16* pb = P + base;

  __shared__ float buf[SQ];
  __shared__ float red[4];
  const int tid = threadIdx.x, lane = tid & 63, wid = tid >> 6;

  float m = -3.4e38f;
  for (int t = tid; t <= s; t += 256){
    float v = scb[(t >> 8) * 65536 + (t & 255)];
    buf[t] = v; m = fmaxf(m, v);
  }
  #pragma unroll
  for (int o = 32; o; o >>= 1) m = fmaxf(m, __shfl_xor(m, o));
  if (lane == 0) red[wid] = m;
  __syncthreads();
  m = fmaxf(fmaxf(red[0], red[1]), fmaxf(red[2], red[3]));
  __syncthreads();

  float sum = 0.f;
  for (int t = tid; t <= s; t += 256){ float e = __expf(buf[t] - m); buf[t] = e; sum += e; }
  #pragma unroll
  for (int o = 32; o; o >>= 1) sum += __shfl_xor(sum, o);
  if (lane == 0) red[wid] = sum;
  __syncthreads();
  sum = red[0] + red[1] + red[2] + red[3];
  const float inv = 1.f / sum;

  const int lim = (i + 1) << 8;         // PV reads keys < (i+1)*256
  for (int t = tid; t < lim; t += 256)
    pb[(t >> 8) * 65536 + (t & 255)] = (t <= s) ? f2h(buf[t] * inv) : (u16)0;
}

__global__ __launch_bounds__(256)
void layernorm_inplace(float* __restrict__ Y, const float* __restrict__ gamma,
                       const float* __restrict__ beta)
{
  float* y = Y + (long long)blockIdx.x * HD;
  const int tid = threadIdx.x, lane = tid & 63, wid = tid >> 6;
  float xv[4];
  float s = 0.f, ss = 0.f;
  #pragma unroll
  for (int i = 0; i < 4; i++){
    float v = y[tid + i * 256];
    xv[i] = v; s += v; ss += v * v;
  }
  #pragma unroll
  for (int o = 32; o; o >>= 1){ s += __shfl_xor(s, o); ss += __shfl_xor(ss, o); }
  __shared__ float r1[4], r2[4];
  if (lane == 0){ r1[wid] = s; r2[wid] = ss; }
  __syncthreads();
  s  = r1[0] + r1[1] + r1[2] + r1[3];
  ss = r2[0] + r2[1] + r2[2] + r2[3];
  const float mu   = s * (1.f / HD);
  const float var  = ss * (1.f / HD) - mu * mu;
  const float rstd = rsqrtf(var + 1e-5f);
  #pragma unroll
  for (int i = 0; i < 4; i++){
    int c = tid + i * 256;
    y[c] = (xv[i] - mu) * rstd * gamma[c] + beta[c];
  }
}

extern "C" void kernel_launch(void* const* d_in, const int* in_sizes, int n_in,
                              void* d_out, int out_size, void* d_ws, size_t ws_size,
                              hipStream_t stream)
{
  const float* x     = (const float*)d_in[0];
  const float* Wq    = (const float*)d_in[1];
  const float* bq    = (const float*)d_in[2];
  const float* Wk    = (const float*)d_in[3];
  const float* bk    = (const float*)d_in[4];
  const float* Wv    = (const float*)d_in[5];
  const float* bv    = (const float*)d_in[6];
  const float* gamma = (const float*)d_in[7];
  const float* beta  = (const float*)d_in[8];
  float* out = (float*)d_out;

  char* wsp = (char*)d_ws;
  size_t off = 0;
  auto alloc = [&](size_t bytes) -> char* {
    char* p = wsp + off;
    off = (off + bytes + 255) & ~(size_t)255;
    return p;
  };

  u16* Wt = (u16*)alloc(3ULL * HD * HD * 2);          // 6.3 MB  (transposed f16)
  u16* QK = (u16*)alloc(2ULL * NTOT * HD * 2);        // 67.1 MB (Q plane, K plane)
  u16* Vt = (u16*)alloc((size_t)NB * HD * SQ * 2);    // 33.6 MB (V transposed f16)

  // region: xh (phase A) aliased with compact SC/P (phase B)
  size_t rem = (ws_size > off) ? (ws_size - off) : 0;
  size_t perb = (size_t)CE * 6;                       // SC f32 + P f16 per batch
  int G = (int)(rem / perb);
  if (G > NB) G = NB;
  if (G < 1)  G = 1;
  u16*   xh = (u16*)(wsp + off);                      // 33.5 MB
  float* SC = (float*)(wsp + off);                    // G * 9.4 MB (compact)
  u16*   P  = (u16*)(wsp + off + (size_t)G * CE * 4); // G * 4.7 MB (compact)

  u16* Qh = QK;
  u16* Kh = QK + (size_t)NTOT * HD;
  float* V = out;   // V fp32 lives in d_out; PV reads V[o] then overwrites o

  prep_x<<<dim3(2048), dim3(256), 0, stream>>>(x, xh);
  prep_w<<<dim3(HD/32, HD/32, 3), dim3(32, 8), 0, stream>>>(Wq, Wk, Wv, Wt);

  // QKV projection: z=0 -> Q f16, z=1 -> K f16, z=2 -> V fp32(d_out) + Vt f16
  gemm8<0><<<dim3(NTOT/256, HD/256, 3), 512, 0, stream>>>(
      xh, Wt, V, QK, Vt, bq, bk, bv,
      HD, HD, HD, HD,
      0LL, (long long)HD * HD, (long long)NTOT * HD);

  for (int g0 = 0; g0 < NB; g0 += G){
    int g = (G < NB - g0) ? G : (NB - g0);
    // scores: triangular compact, 36 tiles of 256x256 per batch
    gemm8<1><<<dim3(NTRI2, 1, g), 512, 0, stream>>>(
        Qh + (size_t)g0 * SQ * HD, Kh + (size_t)g0 * SQ * HD,
        SC, nullptr, nullptr, nullptr, nullptr, nullptr,
        HD, HD, HD, 256,
        (long long)SQ * HD, (long long)SQ * HD, CE);
    softmax_causal<<<dim3(SQ, g), 256, 0, stream>>>(SC, P);
    // PV + residual; A = compact P
    gemm8<2><<<dim3(NT2, HD/256, g), 512, 0, stream>>>(
        P, Vt + (size_t)g0 * HD * SQ,
        out + (size_t)g0 * SQ * HD, nullptr, nullptr, nullptr, nullptr, nullptr,
        SQ, 256, SQ, HD,
        CE, (long long)HD * SQ, (long long)SQ * HD);
  }

  layernorm_inplace<<<dim3(NTOT), 256, 0, stream>>>(out, gamma, beta);
}

// Round 8
// 391.768 us; speedup vs baseline: 1.0132x; 1.0132x over previous
//
#include <hip/hip_runtime.h>

#define SQ 2048
#define HD 1024
#define NB 8
#define NTOT (NB*SQ)
#define NT2 8           // SQ/256
#define NTRI2 36        // NT2*(NT2+1)/2
#define CE ((long long)NTRI2*65536)  // compact score elems per batch (256x256 tiles)

typedef _Float16 f16x8 __attribute__((ext_vector_type(8)));
typedef float f32x4 __attribute__((ext_vector_type(4)));
typedef short s16x8 __attribute__((ext_vector_type(8)));
typedef unsigned short u16;

__device__ __forceinline__ u16 f2h(float x){
  _Float16 h = (_Float16)x;
  u16 u; __builtin_memcpy(&u, &h, 2); return u;
}

// async global->LDS: dest is wave-uniform base, HW adds lane*16
#define STG(gp, lp) __builtin_amdgcn_global_load_lds( \
    (const __attribute__((address_space(1))) unsigned*)(gp), \
    (__attribute__((address_space(3))) unsigned*)(lp), 16, 0, 0)

// ---------------------------------------------------------------------------
// 256x256 f16 MFMA GEMM, BK=32, 8 waves (2M x 4N), wave tile 128x64.
// 4-slot LDS ring (4 x 32KB), 3 tiles in flight, counted vmcnt(8/4/0)
// (round-7 ring, race-verified). ROUND 8: fine-phase compute interleave
// (T3 8-phase analog): per K-tile 4 phases, each {ds_read subtile || issue
// stage loads -> s_barrier -> lgkmcnt(0) -> setprio(1) 8 MFMA setprio(0) ->
// s_barrier}; B-half0 fragments held in regs across the tile.
// LDS tile layout: 128 lines x 128B; logical granule q'=(row>>7)*4+kq stored
// at q'^(line&7); staging source pre-inverse-swizzled (both-sides rule).
// EPI 0: QKV. z=0:Q->f16, z=1:K->f16, z=2:V->fp32(d_out) + Vt f16[H,S]
// EPI 1: scores -> fp32 compact triangular 256^2 tiles (t = tri index)
// EPI 2: PV + residual; A = compact P tiles; K trimmed to (bi+1)*256
// ---------------------------------------------------------------------------
template<int EPI>
__global__ __launch_bounds__(512, 2)
void gemm8(const u16* __restrict__ A, const u16* __restrict__ B,
           float* Cf, u16* Ch, u16* Vt,
           const float* __restrict__ b0, const float* __restrict__ b1,
           const float* __restrict__ b2,
           int K, int lda, int ldb, int ldc,
           long long sA, long long sB, long long sC)
{
  const int z = blockIdx.z;
  int bi, bj, tri = 0;
  if (EPI == 1){                       // triangular decode: t -> (i, j<=i)
    int t = blockIdx.x;
    int i = (int)((sqrtf(8.f * (float)t + 1.f) - 1.f) * 0.5f);
    while ((i + 1) * (i + 2) / 2 <= t) ++i;
    while (i * (i + 1) / 2 > t) --i;
    bi = i;  bj = t - i * (i + 1) / 2;  tri = t;
  } else {
    bi = blockIdx.x;  bj = blockIdx.y;
    if (EPI == 2) tri = bi * (bi + 1) / 2;
  }

  __shared__ short lds[4 * 16384];     // 4 ring bufs x (A 16KB + B 16KB)

  const int tid  = threadIdx.x;
  const int lane = tid & 63, w = tid >> 6;
  const int wm2 = w >> 2, wn4 = w & 3;
  const int lrow = lane & 15, kgrp = lane >> 4;

  const long long rowA = (long long)bi * 256;
  const long long colB = (long long)bj * 256;

  // ---- staging sources: 2 insts per operand, 16B/lane, pre-inverse-swizzled
  const int rt = tid >> 3;                     // 0..63
  const int qp = (tid & 7) ^ (rt & 7);         // logical granule q' (0..7)
  const int kq = qp & 3;                       // k-quad within tile
  const int rh = (qp >> 2) << 7;               // +128 rows if q' >= 4

  const u16 *sAp[2], *sBp[2];
  if (EPI == 2){
    const u16* Pb = A + (long long)z * sA + (long long)tri * 65536;
    #pragma unroll
    for (int i = 0; i < 2; i++)
      sAp[i] = Pb + (i * 64 + rt + rh) * 256 + kq * 8;
  } else {
    const u16* Ab0 = A + (EPI == 0 ? 0LL : (long long)z * sA);
    #pragma unroll
    for (int i = 0; i < 2; i++)
      sAp[i] = Ab0 + (rowA + i * 64 + rt + rh) * (long long)lda + kq * 8;
  }
  {
    const u16* Bb = B + (long long)z * sB;
    #pragma unroll
    for (int i = 0; i < 2; i++)
      sBp[i] = Bb + (colB + i * 64 + rt + rh) * (long long)ldb + kq * 8;
  }

  // ---- fragment read offsets (shorts, within ring buffer) ----
  const int aoff = lrow * 64 + ((((wm2 << 2) | kgrp) ^ (lrow & 7)) << 3);               // + m*1024
  const int boff = 8192 + ((wn4 & 1) * 64 + lrow) * 64
                 + (((((wn4 >> 1) << 2) | kgrp) ^ (lrow & 7)) << 3);                    // + n*1024

  f32x4 acc[8][4];
  const f32x4 zf = {0.f, 0.f, 0.f, 0.f};
  #pragma unroll
  for (int m = 0; m < 8; m++)
    #pragma unroll
    for (int n = 0; n < 4; n++) acc[m][n] = zf;

  int KT = K >> 5;
  if (EPI == 2){ int t = (bi + 1) * 8; if (t < KT) KT = t; }

  auto stage = [&](int b){
    #pragma unroll
    for (int i = 0; i < 2; i++) STG(sAp[i], lds + b * 16384 +        (i * 8 + w) * 512);
    #pragma unroll
    for (int i = 0; i < 2; i++) STG(sBp[i], lds + b * 16384 + 8192 + (i * 8 + w) * 512);
  };
  auto advance = [&](int tS){
    long long advA = 32;
    if (EPI == 2) advA = ((tS & 7) == 7) ? (65536 - 224) : 32;
    sAp[0] += advA; sAp[1] += advA; sBp[0] += 32; sBp[1] += 32;
  };

  // prologue: stage up to 3 tiles into slots 0,1,2
  stage(0); advance(0);
  if (KT > 1){ stage(1); advance(1); }
  if (KT > 2){ stage(2); advance(2); }
  if (KT > 2)      { asm volatile("s_waitcnt vmcnt(8)" ::: "memory"); }
  else if (KT > 1) { asm volatile("s_waitcnt vmcnt(4)" ::: "memory"); }
  else             { asm volatile("s_waitcnt vmcnt(0)" ::: "memory"); }
  __builtin_amdgcn_s_barrier();

  for (int kt = 0; kt < KT; ++kt){
    const short* Ab = lds + (kt & 3) * 16384;
    const bool pf = (kt + 3 < KT);
    const int nb = (kt + 3) & 3;

    f16x8 af[4], bn0[2], bn1[2];

    // ---------- phase 1: A-half0 + B-half0 reads; stage A(kt+3) ----------
    #pragma unroll
    for (int m = 0; m < 4; m++) af[m] = *(const f16x8*)(Ab + aoff + m * 1024);
    #pragma unroll
    for (int n = 0; n < 2; n++) bn0[n] = *(const f16x8*)(Ab + boff + n * 1024);
    if (pf){
      STG(sAp[0], lds + nb * 16384 + (0 * 8 + w) * 512);
      STG(sAp[1], lds + nb * 16384 + (1 * 8 + w) * 512);
    }
    __builtin_amdgcn_sched_barrier(0);
    __builtin_amdgcn_s_barrier();
    asm volatile("s_waitcnt lgkmcnt(0)" ::: "memory");
    __builtin_amdgcn_sched_barrier(0);
    __builtin_amdgcn_s_setprio(1);
    #pragma unroll
    for (int n = 0; n < 2; n++)
      #pragma unroll
      for (int m = 0; m < 4; m++)
        acc[m][n] = __builtin_amdgcn_mfma_f32_16x16x32_f16(af[m], bn0[n], acc[m][n], 0, 0, 0);
    __builtin_amdgcn_s_setprio(0);
    __builtin_amdgcn_s_barrier();

    // ---------- phase 2: B-half1 reads; stage B(kt+3) ----------
    #pragma unroll
    for (int n = 0; n < 2; n++) bn1[n] = *(const f16x8*)(Ab + boff + (2 + n) * 1024);
    if (pf){
      STG(sBp[0], lds + nb * 16384 + 8192 + (0 * 8 + w) * 512);
      STG(sBp[1], lds + nb * 16384 + 8192 + (1 * 8 + w) * 512);
      advance(kt + 3);
    }
    __builtin_amdgcn_sched_barrier(0);
    __builtin_amdgcn_s_barrier();
    asm volatile("s_waitcnt lgkmcnt(0)" ::: "memory");
    __builtin_amdgcn_sched_barrier(0);
    __builtin_amdgcn_s_setprio(1);
    #pragma unroll
    for (int n = 0; n < 2; n++)
      #pragma unroll
      for (int m = 0; m < 4; m++)
        acc[m][2 + n] = __builtin_amdgcn_mfma_f32_16x16x32_f16(af[m], bn1[n], acc[m][2 + n], 0, 0, 0);
    __builtin_amdgcn_s_setprio(0);
    __builtin_amdgcn_s_barrier();

    // ---------- phase 3: A-half1 reads ----------
    #pragma unroll
    for (int m = 0; m < 4; m++) af[m] = *(const f16x8*)(Ab + aoff + (4 + m) * 1024);
    __builtin_amdgcn_sched_barrier(0);
    __builtin_amdgcn_s_barrier();
    asm volatile("s_waitcnt lgkmcnt(0)" ::: "memory");
    __builtin_amdgcn_sched_barrier(0);
    __builtin_amdgcn_s_setprio(1);
    #pragma unroll
    for (int n = 0; n < 2; n++)
      #pragma unroll
      for (int m = 0; m < 4; m++)
        acc[4 + m][2 + n] = __builtin_amdgcn_mfma_f32_16x16x32_f16(af[m], bn1[n], acc[4 + m][2 + n], 0, 0, 0);
    __builtin_amdgcn_s_setprio(0);
    __builtin_amdgcn_s_barrier();

    // ---------- phase 4: no reads (B-half0 held in regs) ----------
    __builtin_amdgcn_s_setprio(1);
    #pragma unroll
    for (int n = 0; n < 2; n++)
      #pragma unroll
      for (int m = 0; m < 4; m++)
        acc[4 + m][n] = __builtin_amdgcn_mfma_f32_16x16x32_f16(af[m], bn0[n], acc[4 + m][n], 0, 0, 0);
    __builtin_amdgcn_s_setprio(0);

    // ---------- end of K-tile: counted wait (never 0 mid-loop) ----------
    const int rem = KT - 1 - kt;
    if (rem >= 3)      { asm volatile("s_waitcnt vmcnt(8)" ::: "memory"); }
    else if (rem == 2) { asm volatile("s_waitcnt vmcnt(4)" ::: "memory"); }
    else if (rem == 1) { asm volatile("s_waitcnt vmcnt(0)" ::: "memory"); }
    if (rem > 0) __builtin_amdgcn_s_barrier();
  }

  // ---- epilogues ----
  if (EPI == 0){
    if (z < 2){
      u16* c = Ch + (long long)z * sC;
      const float* bias = z ? b1 : b0;
      #pragma unroll
      for (int n = 0; n < 4; n++){
        int col = (int)colB + wn4 * 64 + n * 16 + lrow;
        float ba = bias[col];
        #pragma unroll
        for (int m = 0; m < 8; m++){
          long long r = rowA + wm2 * 128 + m * 16 + kgrp * 4;
          #pragma unroll
          for (int j = 0; j < 4; j++)
            c[(r + j) * ldc + col] = f2h(acc[m][n][j] + ba);
        }
      }
    } else {
      #pragma unroll
      for (int n = 0; n < 4; n++){
        int col = (int)colB + wn4 * 64 + n * 16 + lrow;
        float ba = b2[col];
        #pragma unroll
        for (int m = 0; m < 8; m++){
          long long r = rowA + wm2 * 128 + m * 16 + kgrp * 4;
          int bb = (int)(r >> 11);
          int s  = (int)(r & 2047);
          u16* vtc = Vt + ((long long)bb * HD + col) * SQ + s;
          #pragma unroll
          for (int j = 0; j < 4; j++){
            float v = acc[m][n][j] + ba;
            Cf[(r + j) * ldc + col] = v;
            vtc[j] = f2h(v);
          }
        }
      }
    }
  } else if (EPI == 1){
    // compact 256x256 tile store, ld=256
    float* cf = Cf + (long long)z * sC + (long long)tri * 65536;
    #pragma unroll
    for (int n = 0; n < 4; n++){
      int col = wn4 * 64 + n * 16 + lrow;
      #pragma unroll
      for (int m = 0; m < 8; m++){
        int r = wm2 * 128 + m * 16 + kgrp * 4;
        #pragma unroll
        for (int j = 0; j < 4; j++)
          cf[(r + j) * 256 + col] = acc[m][n][j];
      }
    }
  } else {
    float* cf = Cf + (long long)z * sC;
    #pragma unroll
    for (int n = 0; n < 4; n++){
      int col = (int)colB + wn4 * 64 + n * 16 + lrow;
      #pragma unroll
      for (int m = 0; m < 8; m++){
        long long r = rowA + wm2 * 128 + m * 16 + kgrp * 4;
        #pragma unroll
        for (int j = 0; j < 4; j++){
          long long o = (r + j) * ldc + col;
          cf[o] = acc[m][n][j] + cf[o];     // residual: read V then overwrite
        }
      }
    }
  }
}

// x fp32 -> f16 plane
__global__ __launch_bounds__(256)
void prep_x(const float* __restrict__ X, u16* __restrict__ Xh)
{
  const long long n8 = (long long)NTOT * HD / 8;
  for (long long i = (long long)blockIdx.x * 256 + threadIdx.x; i < n8;
       i += (long long)gridDim.x * 256){
    const float* p = X + i * 8;
    float4 a = *(const float4*)p;
    float4 b = *(const float4*)(p + 4);
    float f[8] = {a.x, a.y, a.z, a.w, b.x, b.y, b.z, b.w};
    s16x8 h;
    #pragma unroll
    for (int j = 0; j < 8; j++) h[j] = (short)f2h(f[j]);
    *(s16x8*)&Xh[i * 8] = h;
  }
}

// W[k][n] -> transposed f16 Wt[z][n][k]
__global__ void prep_w(const float* __restrict__ Wq, const float* __restrict__ Wk,
                       const float* __restrict__ Wv, u16* __restrict__ Wt)
{
  __shared__ float t[32][33];
  const float* Win = (blockIdx.z == 0) ? Wq : (blockIdx.z == 1) ? Wk : Wv;
  const size_t zo = (size_t)blockIdx.z * HD * HD;
  int n0 = blockIdx.x * 32, k0 = blockIdx.y * 32;
  int tx = threadIdx.x, ty = threadIdx.y;
  #pragma unroll
  for (int i = 0; i < 4; i++)
    t[ty + 8*i][tx] = Win[(size_t)(k0 + ty + 8*i) * HD + n0 + tx];
  __syncthreads();
  #pragma unroll
  for (int i = 0; i < 4; i++)
    Wt[zo + (size_t)(n0 + ty + 8*i) * HD + k0 + tx] = f2h(t[tx][ty + 8*i]);
}

// softmax over compact triangular SC (256^2 tiles) -> compact P (f16)
__global__ __launch_bounds__(256)
void softmax_causal(const float* __restrict__ SC, u16* __restrict__ P)
{
  const int s = blockIdx.x;
  const int i = s >> 8;                 // 256-row tile
  const int tri = i * (i + 1) / 2;
  const long long base = (long long)blockIdx.y * CE + (long long)tri * 65536
                       + (long long)(s & 255) * 256;
  const float* scb = SC + base;
  u16* pb = P + base;

  __shared__ float buf[SQ];
  __shared__ float red[4];
  const int tid = threadIdx.x, lane = tid & 63, wid = tid >> 6;

  float m = -3.4e38f;
  for (int t = tid; t <= s; t += 256){
    float v = scb[(t >> 8) * 65536 + (t & 255)];
    buf[t] = v; m = fmaxf(m, v);
  }
  #pragma unroll
  for (int o = 32; o; o >>= 1) m = fmaxf(m, __shfl_xor(m, o));
  if (lane == 0) red[wid] = m;
  __syncthreads();
  m = fmaxf(fmaxf(red[0], red[1]), fmaxf(red[2], red[3]));
  __syncthreads();

  float sum = 0.f;
  for (int t = tid; t <= s; t += 256){ float e = __expf(buf[t] - m); buf[t] = e; sum += e; }
  #pragma unroll
  for (int o = 32; o; o >>= 1) sum += __shfl_xor(sum, o);
  if (lane == 0) red[wid] = sum;
  __syncthreads();
  sum = red[0] + red[1] + red[2] + red[3];
  const float inv = 1.f / sum;

  const int lim = (i + 1) << 8;         // PV reads keys < (i+1)*256
  for (int t = tid; t < lim; t += 256)
    pb[(t >> 8) * 65536 + (t & 255)] = (t <= s) ? f2h(buf[t] * inv) : (u16)0;
}

__global__ __launch_bounds__(256)
void layernorm_inplace(float* __restrict__ Y, const float* __restrict__ gamma,
                       const float* __restrict__ beta)
{
  float* y = Y + (long long)blockIdx.x * HD;
  const int tid = threadIdx.x, lane = tid & 63, wid = tid >> 6;
  float xv[4];
  float s = 0.f, ss = 0.f;
  #pragma unroll
  for (int i = 0; i < 4; i++){
    float v = y[tid + i * 256];
    xv[i] = v; s += v; ss += v * v;
  }
  #pragma unroll
  for (int o = 32; o; o >>= 1){ s += __shfl_xor(s, o); ss += __shfl_xor(ss, o); }
  __shared__ float r1[4], r2[4];
  if (lane == 0){ r1[wid] = s; r2[wid] = ss; }
  __syncthreads();
  s  = r1[0] + r1[1] + r1[2] + r1[3];
  ss = r2[0] + r2[1] + r2[2] + r2[3];
  const float mu   = s * (1.f / HD);
  const float var  = ss * (1.f / HD) - mu * mu;
  const float rstd = rsqrtf(var + 1e-5f);
  #pragma unroll
  for (int i = 0; i < 4; i++){
    int c = tid + i * 256;
    y[c] = (xv[i] - mu) * rstd * gamma[c] + beta[c];
  }
}

extern "C" void kernel_launch(void* const* d_in, const int* in_sizes, int n_in,
                              void* d_out, int out_size, void* d_ws, size_t ws_size,
                              hipStream_t stream)
{
  const float* x     = (const float*)d_in[0];
  const float* Wq    = (const float*)d_in[1];
  const float* bq    = (const float*)d_in[2];
  const float* Wk    = (const float*)d_in[3];
  const float* bk    = (const float*)d_in[4];
  const float* Wv    = (const float*)d_in[5];
  const float* bv    = (const float*)d_in[6];
  const float* gamma = (const float*)d_in[7];
  const float* beta  = (const float*)d_in[8];
  float* out = (float*)d_out;

  char* wsp = (char*)d_ws;
  size_t off = 0;
  auto alloc = [&](size_t bytes) -> char* {
    char* p = wsp + off;
    off = (off + bytes + 255) & ~(size_t)255;
    return p;
  };

  u16* Wt = (u16*)alloc(3ULL * HD * HD * 2);          // 6.3 MB  (transposed f16)
  u16* QK = (u16*)alloc(2ULL * NTOT * HD * 2);        // 67.1 MB (Q plane, K plane)
  u16* Vt = (u16*)alloc((size_t)NB * HD * SQ * 2);    // 33.6 MB (V transposed f16)

  // region: xh (phase A) aliased with compact SC/P (phase B)
  size_t rem = (ws_size > off) ? (ws_size - off) : 0;
  size_t perb = (size_t)CE * 6;                       // SC f32 + P f16 per batch
  int G = (int)(rem / perb);
  if (G > NB) G = NB;
  if (G < 1)  G = 1;
  u16*   xh = (u16*)(wsp + off);                      // 33.5 MB
  float* SC = (float*)(wsp + off);                    // G * 9.4 MB (compact)
  u16*   P  = (u16*)(wsp + off + (size_t)G * CE * 4); // G * 4.7 MB (compact)

  u16* Qh = QK;
  u16* Kh = QK + (size_t)NTOT * HD;
  float* V = out;   // V fp32 lives in d_out; PV reads V[o] then overwrites o

  prep_x<<<dim3(2048), dim3(256), 0, stream>>>(x, xh);
  prep_w<<<dim3(HD/32, HD/32, 3), dim3(32, 8), 0, stream>>>(Wq, Wk, Wv, Wt);

  // QKV projection: z=0 -> Q f16, z=1 -> K f16, z=2 -> V fp32(d_out) + Vt f16
  gemm8<0><<<dim3(NTOT/256, HD/256, 3), 512, 0, stream>>>(
      xh, Wt, V, QK, Vt, bq, bk, bv,
      HD, HD, HD, HD,
      0LL, (long long)HD * HD, (long long)NTOT * HD);

  for (int g0 = 0; g0 < NB; g0 += G){
    int g = (G < NB - g0) ? G : (NB - g0);
    // scores: triangular compact, 36 tiles of 256x256 per batch
    gemm8<1><<<dim3(NTRI2, 1, g), 512, 0, stream>>>(
        Qh + (size_t)g0 * SQ * HD, Kh + (size_t)g0 * SQ * HD,
        SC, nullptr, nullptr, nullptr, nullptr, nullptr,
        HD, HD, HD, 256,
        (long long)SQ * HD, (long long)SQ * HD, CE);
    softmax_causal<<<dim3(SQ, g), 256, 0, stream>>>(SC, P);
    // PV + residual; A = compact P
    gemm8<2><<<dim3(NT2, HD/256, g), 512, 0, stream>>>(
        P, Vt + (size_t)g0 * HD * SQ,
        out + (size_t)g0 * SQ * HD, nullptr, nullptr, nullptr, nullptr, nullptr,
        SQ, 256, SQ, HD,
        CE, (long long)HD * SQ, (long long)SQ * HD);
  }

  layernorm_inplace<<<dim3(NTOT), 256, 0, stream>>>(out, gamma, beta);
}

// Round 9
// 354.678 us; speedup vs baseline: 1.1191x; 1.1046x over previous
//
#include <hip/hip_runtime.h>

#define SQ 2048
#define HD 1024
#define NB 8
#define NTOT (NB*SQ)
#define NT2 8           // SQ/256
#define NTRI2 36        // NT2*(NT2+1)/2
#define CE ((long long)NTRI2*65536)  // compact score f32 elems per batch (256x256 tiles)

typedef _Float16 f16x8 __attribute__((ext_vector_type(8)));
typedef float f32x4 __attribute__((ext_vector_type(4)));
typedef short s16x8 __attribute__((ext_vector_type(8)));
typedef unsigned short u16;

__device__ __forceinline__ u16 f2h(float x){
  _Float16 h = (_Float16)x;
  u16 u; __builtin_memcpy(&u, &h, 2); return u;
}

// async global->LDS: dest is wave-uniform base, HW adds lane*16
#define STG(gp, lp) __builtin_amdgcn_global_load_lds( \
    (const __attribute__((address_space(1))) unsigned*)(gp), \
    (__attribute__((address_space(3))) unsigned*)(lp), 16, 0, 0)

// ---------------------------------------------------------------------------
// 256x256 f16 MFMA GEMM, BK=64, 8 waves (2M x 4N), wave tile 128x64.
// ROUND-6 PROVEN CORE (best measured: 758 TF): 2-buffer LDS (2x64KB), stage
// K-tile kt+1 at top of iter kt (loads fly over 4 phase-barrier'd MFMA
// clusters), single vmcnt drain per K-tile via __syncthreads at iter bottom.
// Granule-XOR swizzle: LDS granule (r,g) holds global (r, g^(r&7));
// staging source pre-inverse-swizzled (both-sides rule).
// EPI 0: QKV. z=0:Q->f16, z=1:K->f16, z=2:V->fp32(d_out) + Vt f16[H,S]
// EPI 1: scores -> fp32 compact triangular 256^2 tiles (t = tri index)
// EPI 2: PV + residual; A = compact P tiles IN-PLACE in SC region:
//        per (tile,row): 256 f16 probs in first 512B of the row's 1KB f32
//        span -> u16 layout ld=512, tile stride 131072 u16.
// ---------------------------------------------------------------------------
template<int EPI>
__global__ __launch_bounds__(512, 2)
void gemm8(const u16* __restrict__ A, const u16* __restrict__ B,
           float* Cf, u16* Ch, u16* Vt,
           const float* __restrict__ b0, const float* __restrict__ b1,
           const float* __restrict__ b2,
           int K, int lda, int ldb, int ldc,
           long long sA, long long sB, long long sC)
{
  const int z = blockIdx.z;
  int bi, bj, tri = 0;
  if (EPI == 1){                       // triangular decode: t -> (i, j<=i)
    int t = blockIdx.x;
    int i = (int)((sqrtf(8.f * (float)t + 1.f) - 1.f) * 0.5f);
    while ((i + 1) * (i + 2) / 2 <= t) ++i;
    while (i * (i + 1) / 2 > t) --i;
    bi = i;  bj = t - i * (i + 1) / 2;  tri = t;
  } else {
    bi = blockIdx.x;  bj = blockIdx.y;
    if (EPI == 2) tri = bi * (bi + 1) / 2;
  }

  __shared__ short lds[65536];         // 2 bufs x (A 256x64 + B 256x64) f16

  const int tid  = threadIdx.x;
  const int lane = tid & 63, w = tid >> 6;
  const int wm2 = w >> 2, wn4 = w & 3;
  const int lrow = lane & 15, kgrp = lane >> 4;

  const long long rowA = (long long)bi * 256;
  const long long colB = (long long)bj * 256;

  // ---- staging sources: 4 insts per operand, 16B/lane, pre-swizzled ----
  const int rt = tid >> 3;                       // 0..63: row within 64-row strip
  const int gs = (tid & 7) ^ (rt & 7);           // swizzled source granule

  const u16 *sAp[4], *sBp[4];
  if (EPI == 2){
    // P in-place layout: ld=512 u16, tile stride 131072 u16
    const u16* Pb = A + (long long)z * sA + (long long)tri * 131072;
    #pragma unroll
    for (int i = 0; i < 4; i++)
      sAp[i] = Pb + (i * 64 + rt) * 512 + gs * 8;
  } else {
    const u16* Ab0 = A + (EPI == 0 ? 0LL : (long long)z * sA);
    #pragma unroll
    for (int i = 0; i < 4; i++)
      sAp[i] = Ab0 + (rowA + i * 64 + rt) * (long long)lda + gs * 8;
  }
  {
    const u16* Bb = B + (long long)z * sB;
    #pragma unroll
    for (int i = 0; i < 4; i++)
      sBp[i] = Bb + (colB + i * 64 + rt) * (long long)ldb + gs * 8;
  }

  // wave-uniform LDS dest bases (shorts): inst i of A / B in buffer `buf`
  #define ADST(buf,i) (lds + (buf) * 32768 +         (i) * 4096 + w * 512)
  #define BDST(buf,i) (lds + (buf) * 32768 + 16384 + (i) * 4096 + w * 512)

  // ---- fragment read offsets (shorts), swizzle-matched ----
  const int fl = lrow & 7;
  const int swzk[2] = { ((0 + kgrp) ^ fl) * 8, ((4 + kgrp) ^ fl) * 8 };
  const int arow = (wm2 * 128 + lrow) * 64;          // + m*1024
  const int brow = 16384 + (wn4 * 64 + lrow) * 64;   // + n*1024

  f32x4 acc[8][4];
  const f32x4 zf = {0.f, 0.f, 0.f, 0.f};
  #pragma unroll
  for (int m = 0; m < 8; m++)
    #pragma unroll
    for (int n = 0; n < 4; n++) acc[m][n] = zf;

  int KT = K >> 6;
  if (EPI == 2){ int t = (bi + 1) * 4; if (t < KT) KT = t; }

  // advance staging pointers past just-staged tile tS -> tS+1
  auto advance = [&](int tS){
    long long advA = 64;
    if (EPI == 2) advA = ((tS & 3) == 3) ? (131072 - 192) : 64;
    #pragma unroll
    for (int i = 0; i < 4; i++){ sAp[i] += advA; sBp[i] += 64; }
  };

  // prologue: stage tile 0 into buf0
  #pragma unroll
  for (int i = 0; i < 4; i++) STG(sAp[i], ADST(0, i));
  #pragma unroll
  for (int i = 0; i < 4; i++) STG(sBp[i], BDST(0, i));
  advance(0);
  __syncthreads();

  int cur = 0;
  for (int kt = 0; kt < KT; ++kt){
    const bool pf = (kt + 1 < KT);
    const short* Ab = lds + cur * 32768;
    const int nb = cur ^ 1;

    #pragma unroll
    for (int qm = 0; qm < 2; qm++){
      f16x8 aq[4][2];
      #pragma unroll
      for (int m4 = 0; m4 < 4; m4++)
        #pragma unroll
        for (int ks = 0; ks < 2; ks++)
          aq[m4][ks] = *(const f16x8*)(Ab + arow + (qm * 4 + m4) * 1024 + swzk[ks]);

      #pragma unroll
      for (int qn = 0; qn < 2; qn++){
        // prefetch next K-tile: A-insts at phase 0, B-insts at phase 1
        if (pf && qm == 0 && qn == 0){
          #pragma unroll
          for (int i = 0; i < 4; i++) STG(sAp[i], ADST(nb, i));
        }
        if (pf && qm == 0 && qn == 1){
          #pragma unroll
          for (int i = 0; i < 4; i++) STG(sBp[i], BDST(nb, i));
        }
        f16x8 bq[2][2];
        #pragma unroll
        for (int n2 = 0; n2 < 2; n2++)
          #pragma unroll
          for (int ks = 0; ks < 2; ks++)
            bq[n2][ks] = *(const f16x8*)(Ab + brow + (qn * 2 + n2) * 1024 + swzk[ks]);

        __builtin_amdgcn_s_setprio(1);
        #pragma unroll
        for (int n2 = 0; n2 < 2; n2++)
          #pragma unroll
          for (int m4 = 0; m4 < 4; m4++)
            #pragma unroll
            for (int ks = 0; ks < 2; ks++)
              acc[qm * 4 + m4][qn * 2 + n2] =
                __builtin_amdgcn_mfma_f32_16x16x32_f16(aq[m4][ks], bq[n2][ks],
                                                       acc[qm * 4 + m4][qn * 2 + n2], 0, 0, 0);
        __builtin_amdgcn_s_setprio(0);
        __builtin_amdgcn_s_barrier();        // raw phase barrier (no drain)
      }
    }
    if (pf) advance(kt + 1);
    __syncthreads();                         // once-per-K-tile vmcnt drain + fence
    cur ^= 1;
  }
  #undef ADST
  #undef BDST

  // ---- epilogues ----
  if (EPI == 0){
    if (z < 2){
      u16* c = Ch + (long long)z * sC;
      const float* bias = z ? b1 : b0;
      #pragma unroll
      for (int n = 0; n < 4; n++){
        int col = (int)colB + wn4 * 64 + n * 16 + lrow;
        float ba = bias[col];
        #pragma unroll
        for (int m = 0; m < 8; m++){
          long long r = rowA + wm2 * 128 + m * 16 + kgrp * 4;
          #pragma unroll
          for (int j = 0; j < 4; j++)
            c[(r + j) * ldc + col] = f2h(acc[m][n][j] + ba);
        }
      }
    } else {
      #pragma unroll
      for (int n = 0; n < 4; n++){
        int col = (int)colB + wn4 * 64 + n * 16 + lrow;
        float ba = b2[col];
        #pragma unroll
        for (int m = 0; m < 8; m++){
          long long r = rowA + wm2 * 128 + m * 16 + kgrp * 4;
          int bb = (int)(r >> 11);
          int s  = (int)(r & 2047);
          u16* vtc = Vt + ((long long)bb * HD + col) * SQ + s;
          #pragma unroll
          for (int j = 0; j < 4; j++){
            float v = acc[m][n][j] + ba;
            Cf[(r + j) * ldc + col] = v;
            vtc[j] = f2h(v);
          }
        }
      }
    }
  } else if (EPI == 1){
    // compact 256x256 tile store, ld=256 (f32)
    float* cf = Cf + (long long)z * sC + (long long)tri * 65536;
    #pragma unroll
    for (int n = 0; n < 4; n++){
      int col = wn4 * 64 + n * 16 + lrow;
      #pragma unroll
      for (int m = 0; m < 8; m++){
        int r = wm2 * 128 + m * 16 + kgrp * 4;
        #pragma unroll
        for (int j = 0; j < 4; j++)
          cf[(r + j) * 256 + col] = acc[m][n][j];
      }
    }
  } else {
    float* cf = Cf + (long long)z * sC;
    #pragma unroll
    for (int n = 0; n < 4; n++){
      int col = (int)colB + wn4 * 64 + n * 16 + lrow;
      #pragma unroll
      for (int m = 0; m < 8; m++){
        long long r = rowA + wm2 * 128 + m * 16 + kgrp * 4;
        #pragma unroll
        for (int j = 0; j < 4; j++){
          long long o = (r + j) * ldc + col;
          cf[o] = acc[m][n][j] + cf[o];     // residual: read V then overwrite
        }
      }
    }
  }
}

// x fp32 -> f16 plane
__global__ __launch_bounds__(256)
void prep_x(const float* __restrict__ X, u16* __restrict__ Xh)
{
  const long long n8 = (long long)NTOT * HD / 8;
  for (long long i = (long long)blockIdx.x * 256 + threadIdx.x; i < n8;
       i += (long long)gridDim.x * 256){
    const float* p = X + i * 8;
    float4 a = *(const float4*)p;
    float4 b = *(const float4*)(p + 4);
    float f[8] = {a.x, a.y, a.z, a.w, b.x, b.y, b.z, b.w};
    s16x8 h;
    #pragma unroll
    for (int j = 0; j < 8; j++) h[j] = (short)f2h(f[j]);
    *(s16x8*)&Xh[i * 8] = h;
  }
}

// W[k][n] -> transposed f16 Wt[z][n][k]
__global__ void prep_w(const float* __restrict__ Wq, const float* __restrict__ Wk,
                       const float* __restrict__ Wv, u16* __restrict__ Wt)
{
  __shared__ float t[32][33];
  const float* Win = (blockIdx.z == 0) ? Wq : (blockIdx.z == 1) ? Wk : Wv;
  const size_t zo = (size_t)blockIdx.z * HD * HD;
  int n0 = blockIdx.x * 32, k0 = blockIdx.y * 32;
  int tx = threadIdx.x, ty = threadIdx.y;
  #pragma unroll
  for (int i = 0; i < 4; i++)
    t[ty + 8*i][tx] = Win[(size_t)(k0 + ty + 8*i) * HD + n0 + tx];
  __syncthreads();
  #pragma unroll
  for (int i = 0; i < 4; i++)
    Wt[zo + (size_t)(n0 + ty + 8*i) * HD + k0 + tx] = f2h(t[tx][ty + 8*i]);
}

// softmax over compact triangular SC (256^2 f32 tiles); writes f16 probs
// IN-PLACE into the first 512B of each (tile,row)'s own 1KB f32 row span.
// Safe: all global SC reads complete (followed by __syncthreads) before any
// P write; each block owns exactly one row's spans.
__global__ __launch_bounds__(256)
void softmax_causal(const float* __restrict__ SC, u16* __restrict__ P)
{
  const int s = blockIdx.x;
  const int i = s >> 8;                 // 256-row tile
  const int tri = i * (i + 1) / 2;
  const float* scb = SC + (long long)blockIdx.y * CE + (long long)tri * 65536
                   + (long long)(s & 255) * 256;
  u16* pb = P + (long long)blockIdx.y * (2 * CE) + (long long)tri * 131072
          + (long long)(s & 255) * 512;

  __shared__ float buf[SQ];
  __shared__ float red[4];
  const int tid = threadIdx.x, lane = tid & 63, wid = tid >> 6;

  float m = -3.4e38f;
  for (int t = tid; t <= s; t += 256){
    float v = scb[(t >> 8) * 65536 + (t & 255)];
    buf[t] = v; m = fmaxf(m, v);
  }
  #pragma unroll
  for (int o = 32; o; o >>= 1) m = fmaxf(m, __shfl_xor(m, o));
  if (lane == 0) red[wid] = m;
  __syncthreads();
  m = fmaxf(fmaxf(red[0], red[1]), fmaxf(red[2], red[3]));
  __syncthreads();

  float sum = 0.f;
  for (int t = tid; t <= s; t += 256){ float e = __expf(buf[t] - m); buf[t] = e; sum += e; }
  #pragma unroll
  for (int o = 32; o; o >>= 1) sum += __shfl_xor(sum, o);
  if (lane == 0) red[wid] = sum;
  __syncthreads();
  sum = red[0] + red[1] + red[2] + red[3];
  const float inv = 1.f / sum;

  const int lim = (i + 1) << 8;         // PV reads keys < (i+1)*256
  for (int t = tid; t < lim; t += 256)
    pb[(t >> 8) * 131072 + (t & 255)] = (t <= s) ? f2h(buf[t] * inv) : (u16)0;
}

__global__ __launch_bounds__(256)
void layernorm_inplace(float* __restrict__ Y, const float* __restrict__ gamma,
                       const float* __restrict__ beta)
{
  float* y = Y + (long long)blockIdx.x * HD;
  const int tid = threadIdx.x, lane = tid & 63, wid = tid >> 6;
  float xv[4];
  float s = 0.f, ss = 0.f;
  #pragma unroll
  for (int i = 0; i < 4; i++){
    float v = y[tid + i * 256];
    xv[i] = v; s += v; ss += v * v;
  }
  #pragma unroll
  for (int o = 32; o; o >>= 1){ s += __shfl_xor(s, o); ss += __shfl_xor(ss, o); }
  __shared__ float r1[4], r2[4];
  if (lane == 0){ r1[wid] = s; r2[wid] = ss; }
  __syncthreads();
  s  = r1[0] + r1[1] + r1[2] + r1[3];
  ss = r2[0] + r2[1] + r2[2] + r2[3];
  const float mu   = s * (1.f / HD);
  const float var  = ss * (1.f / HD) - mu * mu;
  const float rstd = rsqrtf(var + 1e-5f);
  #pragma unroll
  for (int i = 0; i < 4; i++){
    int c = tid + i * 256;
    y[c] = (xv[i] - mu) * rstd * gamma[c] + beta[c];
  }
}

extern "C" void kernel_launch(void* const* d_in, const int* in_sizes, int n_in,
                              void* d_out, int out_size, void* d_ws, size_t ws_size,
                              hipStream_t stream)
{
  const float* x     = (const float*)d_in[0];
  const float* Wq    = (const float*)d_in[1];
  const float* bq    = (const float*)d_in[2];
  const float* Wk    = (const float*)d_in[3];
  const float* bk    = (const float*)d_in[4];
  const float* Wv    = (const float*)d_in[5];
  const float* bv    = (const float*)d_in[6];
  const float* gamma = (const float*)d_in[7];
  const float* beta  = (const float*)d_in[8];
  float* out = (float*)d_out;

  char* wsp = (char*)d_ws;
  size_t off = 0;
  auto alloc = [&](size_t bytes) -> char* {
    char* p = wsp + off;
    off = (off + bytes + 255) & ~(size_t)255;
    return p;
  };

  u16* Wt = (u16*)alloc(3ULL * HD * HD * 2);          // 6.3 MB  (transposed f16)
  u16* QK = (u16*)alloc(2ULL * NTOT * HD * 2);        // 67.1 MB (Q plane, K plane)
  u16* Vt = (u16*)alloc((size_t)NB * HD * SQ * 2);    // 33.6 MB (V transposed f16)

  // region: xh (phase A) aliased with compact SC (phase B; P lives inside SC)
  size_t rem = (ws_size > off) ? (ws_size - off) : 0;
  size_t perb = (size_t)CE * 4;                       // 9.4 MB per batch
  int G = (int)(rem / perb);
  if (G > NB) G = NB;
  if (G < 1)  G = 1;
  u16*   xh = (u16*)(wsp + off);                      // 33.5 MB
  float* SC = (float*)(wsp + off);                    // G * 9.4 MB (compact, P in-place)

  u16* Qh = QK;
  u16* Kh = QK + (size_t)NTOT * HD;
  float* V = out;   // V fp32 lives in d_out; PV reads V[o] then overwrites o

  prep_x<<<dim3(2048), dim3(256), 0, stream>>>(x, xh);
  prep_w<<<dim3(HD/32, HD/32, 3), dim3(32, 8), 0, stream>>>(Wq, Wk, Wv, Wt);

  // QKV projection: z=0 -> Q f16, z=1 -> K f16, z=2 -> V fp32(d_out) + Vt f16
  gemm8<0><<<dim3(NTOT/256, HD/256, 3), 512, 0, stream>>>(
      xh, Wt, V, QK, Vt, bq, bk, bv,
      HD, HD, HD, HD,
      0LL, (long long)HD * HD, (long long)NTOT * HD);

  for (int g0 = 0; g0 < NB; g0 += G){
    int g = (G < NB - g0) ? G : (NB - g0);
    // scores: triangular compact, 36 tiles of 256x256 per batch
    gemm8<1><<<dim3(NTRI2, 1, g), 512, 0, stream>>>(
        Qh + (size_t)g0 * SQ * HD, Kh + (size_t)g0 * SQ * HD,
        SC, nullptr, nullptr, nullptr, nullptr, nullptr,
        HD, HD, HD, 256,
        (long long)SQ * HD, (long long)SQ * HD, CE);
    softmax_causal<<<dim3(SQ, g), 256, 0, stream>>>(SC, (u16*)SC);
    // PV + residual; A = in-place compact P (u16 view of SC region)
    gemm8<2><<<dim3(NT2, HD/256, g), 512, 0, stream>>>(
        (const u16*)SC, Vt + (size_t)g0 * HD * SQ,
        out + (size_t)g0 * SQ * HD, nullptr, nullptr, nullptr, nullptr, nullptr,
        SQ, 512, SQ, HD,
        2 * CE, (long long)HD * SQ, (long long)SQ * HD);
  }

  layernorm_inplace<<<dim3(NTOT), 256, 0, stream>>>(out, gamma, beta);
}

// Round 10
// 345.263 us; speedup vs baseline: 1.1497x; 1.0273x over previous
//
#include <hip/hip_runtime.h>

#define SQ 2048
#define HD 1024
#define NB 8
#define NTOT (NB*SQ)
#define NT2 8           // SQ/256
#define NTRI2 36        // NT2*(NT2+1)/2
#define CE ((long long)NTRI2*65536)  // compact score f32 elems per batch (256x256 tiles)

typedef _Float16 f16x8 __attribute__((ext_vector_type(8)));
typedef float f32x4 __attribute__((ext_vector_type(4)));
typedef short s16x8 __attribute__((ext_vector_type(8)));
typedef unsigned short u16;

__device__ __forceinline__ u16 f2h(float x){
  _Float16 h = (_Float16)x;
  u16 u; __builtin_memcpy(&u, &h, 2); return u;
}

// async global->LDS: dest is wave-uniform base, HW adds lane*16
#define STG(gp, lp) __builtin_amdgcn_global_load_lds( \
    (const __attribute__((address_space(1))) unsigned*)(gp), \
    (__attribute__((address_space(3))) unsigned*)(lp), 16, 0, 0)

// ---------------------------------------------------------------------------
// 256x256 f16 MFMA GEMM, BK=64, 8 waves (2M x 4N), wave tile 128x64.
// Round-10 core: 2-buffer LDS (2x64KB); all 8 stage-DMAs for tile kt+1
// issued at top of iter kt; NO intra-tile barriers (free-running waves
// de-phase -> cross-wave LDS/MFMA overlap); single __syncthreads per K-tile
// carries the dbuf hazard (drains each wave's DMA + barrier).
// Dataflow fixes vs rounds 6-8: B fragments read ONCE per K-tile (24 vs 32
// ds_read_b128/wave), and MFMA loops ordered ks-OUTER so 16 independent
// MFMAs separate dependent accumulator writes.
// Granule-XOR swizzle: LDS granule (r,g) holds global (r, g^(r&7));
// staging source pre-inverse-swizzled (both-sides rule).
// EPI 0: QKV. z=0:Q->f16, z=1:K->f16, z=2:V->fp32(d_out) + Vt f16[H,S]
// EPI 1: scores -> fp32 compact triangular 256^2 tiles (t = tri index)
// EPI 2: PV + residual; A = compact P tiles in-place in SC region
//        (ld=512 u16, tile stride 131072 u16); K trimmed to (bi+1)*256
// ---------------------------------------------------------------------------
template<int EPI>
__global__ __launch_bounds__(512, 2)
void gemm8(const u16* __restrict__ A, const u16* __restrict__ B,
           float* Cf, u16* Ch, u16* Vt,
           const float* __restrict__ b0, const float* __restrict__ b1,
           const float* __restrict__ b2,
           int K, int lda, int ldb, int ldc,
           long long sA, long long sB, long long sC)
{
  const int z = blockIdx.z;
  int bi, bj, tri = 0;
  if (EPI == 1){                       // triangular decode: t -> (i, j<=i)
    int t = blockIdx.x;
    int i = (int)((sqrtf(8.f * (float)t + 1.f) - 1.f) * 0.5f);
    while ((i + 1) * (i + 2) / 2 <= t) ++i;
    while (i * (i + 1) / 2 > t) --i;
    bi = i;  bj = t - i * (i + 1) / 2;  tri = t;
  } else {
    bi = blockIdx.x;  bj = blockIdx.y;
    if (EPI == 2) tri = bi * (bi + 1) / 2;
  }

  __shared__ short lds[65536];         // 2 bufs x (A 256x64 + B 256x64) f16

  const int tid  = threadIdx.x;
  const int lane = tid & 63, w = tid >> 6;
  const int wm2 = w >> 2, wn4 = w & 3;
  const int lrow = lane & 15, kgrp = lane >> 4;

  const long long rowA = (long long)bi * 256;
  const long long colB = (long long)bj * 256;

  // ---- staging sources: 4 insts per operand, 16B/lane, pre-swizzled ----
  const int rt = tid >> 3;                       // 0..63: row within 64-row strip
  const int gs = (tid & 7) ^ (rt & 7);           // swizzled source granule

  const u16 *sAp[4], *sBp[4];
  if (EPI == 2){
    // P in-place layout: ld=512 u16, tile stride 131072 u16
    const u16* Pb = A + (long long)z * sA + (long long)tri * 131072;
    #pragma unroll
    for (int i = 0; i < 4; i++)
      sAp[i] = Pb + (i * 64 + rt) * 512 + gs * 8;
  } else {
    const u16* Ab0 = A + (EPI == 0 ? 0LL : (long long)z * sA);
    #pragma unroll
    for (int i = 0; i < 4; i++)
      sAp[i] = Ab0 + (rowA + i * 64 + rt) * (long long)lda + gs * 8;
  }
  {
    const u16* Bb = B + (long long)z * sB;
    #pragma unroll
    for (int i = 0; i < 4; i++)
      sBp[i] = Bb + (colB + i * 64 + rt) * (long long)ldb + gs * 8;
  }

  // wave-uniform LDS dest bases (shorts): inst i of A / B in buffer `buf`
  #define ADST(buf,i) (lds + (buf) * 32768 +         (i) * 4096 + w * 512)
  #define BDST(buf,i) (lds + (buf) * 32768 + 16384 + (i) * 4096 + w * 512)

  // ---- fragment read offsets (shorts), swizzle-matched ----
  const int fl = lrow & 7;
  const int swzk[2] = { ((0 + kgrp) ^ fl) * 8, ((4 + kgrp) ^ fl) * 8 };
  const int arow = (wm2 * 128 + lrow) * 64;          // + m*1024
  const int brow = 16384 + (wn4 * 64 + lrow) * 64;   // + n*1024

  f32x4 acc[8][4];
  const f32x4 zf = {0.f, 0.f, 0.f, 0.f};
  #pragma unroll
  for (int m = 0; m < 8; m++)
    #pragma unroll
    for (int n = 0; n < 4; n++) acc[m][n] = zf;

  int KT = K >> 6;
  if (EPI == 2){ int t = (bi + 1) * 4; if (t < KT) KT = t; }

  // advance staging pointers past just-staged tile tS -> tS+1
  auto advance = [&](int tS){
    long long advA = 64;
    if (EPI == 2) advA = ((tS & 3) == 3) ? (131072 - 192) : 64;
    #pragma unroll
    for (int i = 0; i < 4; i++){ sAp[i] += advA; sBp[i] += 64; }
  };

  // prologue: stage tile 0 into buf0
  #pragma unroll
  for (int i = 0; i < 4; i++) STG(sAp[i], ADST(0, i));
  #pragma unroll
  for (int i = 0; i < 4; i++) STG(sBp[i], BDST(0, i));
  advance(0);
  __syncthreads();

  int cur = 0;
  for (int kt = 0; kt < KT; ++kt){
    const bool pf = (kt + 1 < KT);
    const short* Ab = lds + cur * 32768;
    const int nb = cur ^ 1;

    // issue all prefetch DMAs for tile kt+1 up front (fly over whole tile)
    if (pf){
      #pragma unroll
      for (int i = 0; i < 4; i++) STG(sAp[i], ADST(nb, i));
      #pragma unroll
      for (int i = 0; i < 4; i++) STG(sBp[i], BDST(nb, i));
      advance(kt + 1);
    }

    // B fragments: read once per K-tile (8 x ds_read_b128)
    f16x8 bq[4][2];
    #pragma unroll
    for (int n = 0; n < 4; n++)
      #pragma unroll
      for (int ks = 0; ks < 2; ks++)
        bq[n][ks] = *(const f16x8*)(Ab + brow + n * 1024 + swzk[ks]);

    #pragma unroll
    for (int qm = 0; qm < 2; qm++){
      f16x8 aq[4][2];
      #pragma unroll
      for (int m4 = 0; m4 < 4; m4++)
        #pragma unroll
        for (int ks = 0; ks < 2; ks++)
          aq[m4][ks] = *(const f16x8*)(Ab + arow + (qm * 4 + m4) * 1024 + swzk[ks]);

      // ks OUTER: 16 independent MFMAs between dependent acc reuses
      __builtin_amdgcn_s_setprio(1);
      #pragma unroll
      for (int ks = 0; ks < 2; ks++)
        #pragma unroll
        for (int n = 0; n < 4; n++)
          #pragma unroll
          for (int m4 = 0; m4 < 4; m4++)
            acc[qm * 4 + m4][n] =
              __builtin_amdgcn_mfma_f32_16x16x32_f16(aq[m4][ks], bq[n][ks],
                                                     acc[qm * 4 + m4][n], 0, 0, 0);
      __builtin_amdgcn_s_setprio(0);
    }

    __syncthreads();      // once per K-tile: per-wave vmcnt/lgkm drain + barrier
    cur ^= 1;
  }
  #undef ADST
  #undef BDST

  // ---- epilogues ----
  if (EPI == 0){
    if (z < 2){
      u16* c = Ch + (long long)z * sC;
      const float* bias = z ? b1 : b0;
      #pragma unroll
      for (int n = 0; n < 4; n++){
        int col = (int)colB + wn4 * 64 + n * 16 + lrow;
        float ba = bias[col];
        #pragma unroll
        for (int m = 0; m < 8; m++){
          long long r = rowA + wm2 * 128 + m * 16 + kgrp * 4;
          #pragma unroll
          for (int j = 0; j < 4; j++)
            c[(r + j) * ldc + col] = f2h(acc[m][n][j] + ba);
        }
      }
    } else {
      #pragma unroll
      for (int n = 0; n < 4; n++){
        int col = (int)colB + wn4 * 64 + n * 16 + lrow;
        float ba = b2[col];
        #pragma unroll
        for (int m = 0; m < 8; m++){
          long long r = rowA + wm2 * 128 + m * 16 + kgrp * 4;
          int bb = (int)(r >> 11);
          int s  = (int)(r & 2047);
          u16* vtc = Vt + ((long long)bb * HD + col) * SQ + s;
          #pragma unroll
          for (int j = 0; j < 4; j++){
            float v = acc[m][n][j] + ba;
            Cf[(r + j) * ldc + col] = v;
            vtc[j] = f2h(v);
          }
        }
      }
    }
  } else if (EPI == 1){
    // compact 256x256 tile store, ld=256 (f32)
    float* cf = Cf + (long long)z * sC + (long long)tri * 65536;
    #pragma unroll
    for (int n = 0; n < 4; n++){
      int col = wn4 * 64 + n * 16 + lrow;
      #pragma unroll
      for (int m = 0; m < 8; m++){
        int r = wm2 * 128 + m * 16 + kgrp * 4;
        #pragma unroll
        for (int j = 0; j < 4; j++)
          cf[(r + j) * 256 + col] = acc[m][n][j];
      }
    }
  } else {
    float* cf = Cf + (long long)z * sC;
    #pragma unroll
    for (int n = 0; n < 4; n++){
      int col = (int)colB + wn4 * 64 + n * 16 + lrow;
      #pragma unroll
      for (int m = 0; m < 8; m++){
        long long r = rowA + wm2 * 128 + m * 16 + kgrp * 4;
        #pragma unroll
        for (int j = 0; j < 4; j++){
          long long o = (r + j) * ldc + col;
          cf[o] = acc[m][n][j] + cf[o];     // residual: read V then overwrite
        }
      }
    }
  }
}

// x fp32 -> f16 plane
__global__ __launch_bounds__(256)
void prep_x(const float* __restrict__ X, u16* __restrict__ Xh)
{
  const long long n8 = (long long)NTOT * HD / 8;
  for (long long i = (long long)blockIdx.x * 256 + threadIdx.x; i < n8;
       i += (long long)gridDim.x * 256){
    const float* p = X + i * 8;
    float4 a = *(const float4*)p;
    float4 b = *(const float4*)(p + 4);
    float f[8] = {a.x, a.y, a.z, a.w, b.x, b.y, b.z, b.w};
    s16x8 h;
    #pragma unroll
    for (int j = 0; j < 8; j++) h[j] = (short)f2h(f[j]);
    *(s16x8*)&Xh[i * 8] = h;
  }
}

// W[k][n] -> transposed f16 Wt[z][n][k]
__global__ void prep_w(const float* __restrict__ Wq, const float* __restrict__ Wk,
                       const float* __restrict__ Wv, u16* __restrict__ Wt)
{
  __shared__ float t[32][33];
  const float* Win = (blockIdx.z == 0) ? Wq : (blockIdx.z == 1) ? Wk : Wv;
  const size_t zo = (size_t)blockIdx.z * HD * HD;
  int n0 = blockIdx.x * 32, k0 = blockIdx.y * 32;
  int tx = threadIdx.x, ty = threadIdx.y;
  #pragma unroll
  for (int i = 0; i < 4; i++)
    t[ty + 8*i][tx] = Win[(size_t)(k0 + ty + 8*i) * HD + n0 + tx];
  __syncthreads();
  #pragma unroll
  for (int i = 0; i < 4; i++)
    Wt[zo + (size_t)(n0 + ty + 8*i) * HD + k0 + tx] = f2h(t[tx][ty + 8*i]);
}

// softmax over compact triangular SC (256^2 f32 tiles); writes f16 probs
// IN-PLACE into the first 512B of each (tile,row)'s own 1KB f32 row span.
__global__ __launch_bounds__(256)
void softmax_causal(const float* __restrict__ SC, u16* __restrict__ P)
{
  const int s = blockIdx.x;
  const int i = s >> 8;                 // 256-row tile
  const int tri = i * (i + 1) / 2;
  const float* scb = SC + (long long)blockIdx.y * CE + (long long)tri * 65536
                   + (long long)(s & 255) * 256;
  u16* pb = P + (long long)blockIdx.y * (2 * CE) + (long long)tri * 131072
          + (long long)(s & 255) * 512;

  __shared__ float buf[SQ];
  __shared__ float red[4];
  const int tid = threadIdx.x, lane = tid & 63, wid = tid >> 6;

  float m = -3.4e38f;
  for (int t = tid; t <= s; t += 256){
    float v = scb[(t >> 8) * 65536 + (t & 255)];
    buf[t] = v; m = fmaxf(m, v);
  }
  #pragma unroll
  for (int o = 32; o; o >>= 1) m = fmaxf(m, __shfl_xor(m, o));
  if (lane == 0) red[wid] = m;
  __syncthreads();
  m = fmaxf(fmaxf(red[0], red[1]), fmaxf(red[2], red[3]));
  __syncthreads();

  float sum = 0.f;
  for (int t = tid; t <= s; t += 256){ float e = __expf(buf[t] - m); buf[t] = e; sum += e; }
  #pragma unroll
  for (int o = 32; o; o >>= 1) sum += __shfl_xor(sum, o);
  if (lane == 0) red[wid] = sum;
  __syncthreads();
  sum = red[0] + red[1] + red[2] + red[3];
  const float inv = 1.f / sum;

  const int lim = (i + 1) << 8;         // PV reads keys < (i+1)*256
  for (int t = tid; t < lim; t += 256)
    pb[(t >> 8) * 131072 + (t & 255)] = (t <= s) ? f2h(buf[t] * inv) : (u16)0;
}

__global__ __launch_bounds__(256)
void layernorm_inplace(float* __restrict__ Y, const float* __restrict__ gamma,
                       const float* __restrict__ beta)
{
  float* y = Y + (long long)blockIdx.x * HD;
  const int tid = threadIdx.x, lane = tid & 63, wid = tid >> 6;
  float xv[4];
  float s = 0.f, ss = 0.f;
  #pragma unroll
  for (int i = 0; i < 4; i++){
    float v = y[tid + i * 256];
    xv[i] = v; s += v; ss += v * v;
  }
  #pragma unroll
  for (int o = 32; o; o >>= 1){ s += __shfl_xor(s, o); ss += __shfl_xor(ss, o); }
  __shared__ float r1[4], r2[4];
  if (lane == 0){ r1[wid] = s; r2[wid] = ss; }
  __syncthreads();
  s  = r1[0] + r1[1] + r1[2] + r1[3];
  ss = r2[0] + r2[1] + r2[2] + r2[3];
  const float mu   = s * (1.f / HD);
  const float var  = ss * (1.f / HD) - mu * mu;
  const float rstd = rsqrtf(var + 1e-5f);
  #pragma unroll
  for (int i = 0; i < 4; i++){
    int c = tid + i * 256;
    y[c] = (xv[i] - mu) * rstd * gamma[c] + beta[c];
  }
}

extern "C" void kernel_launch(void* const* d_in, const int* in_sizes, int n_in,
                              void* d_out, int out_size, void* d_ws, size_t ws_size,
                              hipStream_t stream)
{
  const float* x     = (const float*)d_in[0];
  const float* Wq    = (const float*)d_in[1];
  const float* bq    = (const float*)d_in[2];
  const float* Wk    = (const float*)d_in[3];
  const float* bk    = (const float*)d_in[4];
  const float* Wv    = (const float*)d_in[5];
  const float* bv    = (const float*)d_in[6];
  const float* gamma = (const float*)d_in[7];
  const float* beta  = (const float*)d_in[8];
  float* out = (float*)d_out;

  char* wsp = (char*)d_ws;
  size_t off = 0;
  auto alloc = [&](size_t bytes) -> char* {
    char* p = wsp + off;
    off = (off + bytes + 255) & ~(size_t)255;
    return p;
  };

  u16* Wt = (u16*)alloc(3ULL * HD * HD * 2);          // 6.3 MB  (transposed f16)
  u16* QK = (u16*)alloc(2ULL * NTOT * HD * 2);        // 67.1 MB (Q plane, K plane)
  u16* Vt = (u16*)alloc((size_t)NB * HD * SQ * 2);    // 33.6 MB (V transposed f16)

  // region: xh (phase A) aliased with compact SC (phase B; P lives inside SC)
  size_t rem = (ws_size > off) ? (ws_size - off) : 0;
  size_t perb = (size_t)CE * 4;                       // 9.4 MB per batch
  int G = (int)(rem / perb);
  if (G > NB) G = NB;
  if (G < 1)  G = 1;
  u16*   xh = (u16*)(wsp + off);                      // 33.5 MB
  float* SC = (float*)(wsp + off);                    // G * 9.4 MB (compact, P in-place)

  u16* Qh = QK;
  u16* Kh = QK + (size_t)NTOT * HD;
  float* V = out;   // V fp32 lives in d_out; PV reads V[o] then overwrites o

  prep_x<<<dim3(2048), dim3(256), 0, stream>>>(x, xh);
  prep_w<<<dim3(HD/32, HD/32, 3), dim3(32, 8), 0, stream>>>(Wq, Wk, Wv, Wt);

  // QKV projection: z=0 -> Q f16, z=1 -> K f16, z=2 -> V fp32(d_out) + Vt f16
  gemm8<0><<<dim3(NTOT/256, HD/256, 3), 512, 0, stream>>>(
      xh, Wt, V, QK, Vt, bq, bk, bv,
      HD, HD, HD, HD,
      0LL, (long long)HD * HD, (long long)NTOT * HD);

  for (int g0 = 0; g0 < NB; g0 += G){
    int g = (G < NB - g0) ? G : (NB - g0);
    // scores: triangular compact, 36 tiles of 256x256 per batch
    gemm8<1><<<dim3(NTRI2, 1, g), 512, 0, stream>>>(
        Qh + (size_t)g0 * SQ * HD, Kh + (size_t)g0 * SQ * HD,
        SC, nullptr, nullptr, nullptr, nullptr, nullptr,
        HD, HD, HD, 256,
        (long long)SQ * HD, (long long)SQ * HD, CE);
    softmax_causal<<<dim3(SQ, g), 256, 0, stream>>>(SC, (u16*)SC);
    // PV + residual; A = in-place compact P (u16 view of SC region)
    gemm8<2><<<dim3(NT2, HD/256, g), 512, 0, stream>>>(
        (const u16*)SC, Vt + (size_t)g0 * HD * SQ,
        out + (size_t)g0 * SQ * HD, nullptr, nullptr, nullptr, nullptr, nullptr,
        SQ, 512, SQ, HD,
        2 * CE, (long long)HD * SQ, (long long)SQ * HD);
  }

  layernorm_inplace<<<dim3(NTOT), 256, 0, stream>>>(out, gamma, beta);
}

// Round 11
// 339.839 us; speedup vs baseline: 1.1680x; 1.0160x over previous
//
#include <hip/hip_runtime.h>

#define SQ 2048
#define HD 1024
#define NB 8
#define NT2 8           // SQ/256
#define NTOT (NB*SQ)
#define CE ((long long)72*32768)  // compact score f32 elems per batch (72 tiles of 128x256)

typedef _Float16 f16x8 __attribute__((ext_vector_type(8)));
typedef float f32x4 __attribute__((ext_vector_type(4)));
typedef short s16x8 __attribute__((ext_vector_type(8)));
typedef unsigned short u16;

__device__ __forceinline__ u16 f2h(float x){
  _Float16 h = (_Float16)x;
  u16 u; __builtin_memcpy(&u, &h, 2); return u;
}

// triangular base for 128-row strips: #tiles in strips < i  (strip t has floor(t/2)+1 tiles)
__device__ __forceinline__ int TB128(int i){
  int m = i >> 1;
  return (i & 1) ? (m + 1) * (m + 1) : m * m + m;
}

// async global->LDS: dest is wave-uniform base, HW adds lane*16
#define STG(gp, lp) __builtin_amdgcn_global_load_lds( \
    (const __attribute__((address_space(1))) unsigned*)(gp), \
    (__attribute__((address_space(3))) unsigned*)(lp), 16, 0, 0)

// ---------------------------------------------------------------------------
// 256x256 f16 MFMA GEMM, BK=64, 8 waves (2M x 4N), wave tile 128x64.
// Round-10 proven core: 2-buffer LDS; all 8 stage-DMAs for tile kt+1 issued
// at top of iter kt; no intra-tile barriers; single __syncthreads per K-tile.
// B fragments read once per K-tile; MFMA ks-outer. Granule-XOR swizzle:
// LDS granule (r,g) holds global (r, g^(r&7)); source pre-inverse-swizzled.
// EPI 0: QKV. z=0:Q->f16, z=1:K->f16, z=2:V->fp32(d_out) + Vt f16[H,S]
// EPI 2: PV + residual; A = compact P in 128x256 strips (u16 ld=512 in-place
//        in SC region, strip tile stride 65536 u16); K trimmed to (bi+1)*256
// ---------------------------------------------------------------------------
template<int EPI>
__global__ __launch_bounds__(512, 2)
void gemm8(const u16* __restrict__ A, const u16* __restrict__ B,
           float* Cf, u16* Ch, u16* Vt,
           const float* __restrict__ b0, const float* __restrict__ b1,
           const float* __restrict__ b2,
           int K, int lda, int ldb, int ldc,
           long long sA, long long sB, long long sC)
{
  const int z = blockIdx.z;
  const int bi = blockIdx.x, bj = blockIdx.y;

  __shared__ short lds[65536];         // 2 bufs x (A 256x64 + B 256x64) f16

  const int tid  = threadIdx.x;
  const int lane = tid & 63, w = tid >> 6;
  const int wm2 = w >> 2, wn4 = w & 3;
  const int lrow = lane & 15, kgrp = lane >> 4;

  const long long rowA = (long long)bi * 256;
  const long long colB = (long long)bj * 256;

  // ---- staging sources: 4 insts per operand, 16B/lane, pre-swizzled ----
  const int rt = tid >> 3;                       // 0..63: row within 64-row strip
  const int gs = (tid & 7) ^ (rt & 7);           // swizzled source granule

  const u16 *sAp[4], *sBp[4];
  if (EPI == 2){
    // P in 128x256 compact strips: rows 0..127 -> strip 2bi, 128..255 -> 2bi+1
    const u16* P0 = A + (long long)z * sA + (long long)(bi * bi + bi) * 65536;
    const u16* P1 = A + (long long)z * sA + (long long)((bi + 1) * (bi + 1)) * 65536;
    sAp[0] = P0 + (      rt) * 512 + gs * 8;
    sAp[1] = P0 + (64  + rt) * 512 + gs * 8;
    sAp[2] = P1 + (      rt) * 512 + gs * 8;
    sAp[3] = P1 + (64  + rt) * 512 + gs * 8;
  } else {
    const u16* Ab0 = A;
    #pragma unroll
    for (int i = 0; i < 4; i++)
      sAp[i] = Ab0 + (rowA + i * 64 + rt) * (long long)lda + gs * 8;
  }
  {
    const u16* Bb = B + (long long)z * sB;
    #pragma unroll
    for (int i = 0; i < 4; i++)
      sBp[i] = Bb + (colB + i * 64 + rt) * (long long)ldb + gs * 8;
  }

  #define ADST(buf,i) (lds + (buf) * 32768 +         (i) * 4096 + w * 512)
  #define BDST(buf,i) (lds + (buf) * 32768 + 16384 + (i) * 4096 + w * 512)

  const int fl = lrow & 7;
  const int swzk[2] = { ((0 + kgrp) ^ fl) * 8, ((4 + kgrp) ^ fl) * 8 };
  const int arow = (wm2 * 128 + lrow) * 64;          // + m*1024
  const int brow = 16384 + (wn4 * 64 + lrow) * 64;   // + n*1024

  f32x4 acc[8][4];
  const f32x4 zf = {0.f, 0.f, 0.f, 0.f};
  #pragma unroll
  for (int m = 0; m < 8; m++)
    #pragma unroll
    for (int n = 0; n < 4; n++) acc[m][n] = zf;

  int KT = K >> 6;
  if (EPI == 2){ int t = (bi + 1) * 4; if (t < KT) KT = t; }

  auto advance = [&](int tS){
    long long advA = 64;
    if (EPI == 2) advA = ((tS & 3) == 3) ? (65536 - 192) : 64;
    #pragma unroll
    for (int i = 0; i < 4; i++){ sAp[i] += advA; sBp[i] += 64; }
  };

  #pragma unroll
  for (int i = 0; i < 4; i++) STG(sAp[i], ADST(0, i));
  #pragma unroll
  for (int i = 0; i < 4; i++) STG(sBp[i], BDST(0, i));
  advance(0);
  __syncthreads();

  int cur = 0;
  for (int kt = 0; kt < KT; ++kt){
    const bool pf = (kt + 1 < KT);
    const short* Ab = lds + cur * 32768;
    const int nb = cur ^ 1;

    if (pf){
      #pragma unroll
      for (int i = 0; i < 4; i++) STG(sAp[i], ADST(nb, i));
      #pragma unroll
      for (int i = 0; i < 4; i++) STG(sBp[i], BDST(nb, i));
      advance(kt + 1);
    }

    f16x8 bq[4][2];
    #pragma unroll
    for (int n = 0; n < 4; n++)
      #pragma unroll
      for (int ks = 0; ks < 2; ks++)
        bq[n][ks] = *(const f16x8*)(Ab + brow + n * 1024 + swzk[ks]);

    #pragma unroll
    for (int qm = 0; qm < 2; qm++){
      f16x8 aq[4][2];
      #pragma unroll
      for (int m4 = 0; m4 < 4; m4++)
        #pragma unroll
        for (int ks = 0; ks < 2; ks++)
          aq[m4][ks] = *(const f16x8*)(Ab + arow + (qm * 4 + m4) * 1024 + swzk[ks]);

      __builtin_amdgcn_s_setprio(1);
      #pragma unroll
      for (int ks = 0; ks < 2; ks++)
        #pragma unroll
        for (int n = 0; n < 4; n++)
          #pragma unroll
          for (int m4 = 0; m4 < 4; m4++)
            acc[qm * 4 + m4][n] =
              __builtin_amdgcn_mfma_f32_16x16x32_f16(aq[m4][ks], bq[n][ks],
                                                     acc[qm * 4 + m4][n], 0, 0, 0);
      __builtin_amdgcn_s_setprio(0);
    }

    __syncthreads();
    cur ^= 1;
  }
  #undef ADST
  #undef BDST

  // ---- epilogues ----
  if (EPI == 0){
    if (z < 2){
      u16* c = Ch + (long long)z * sC;
      const float* bias = z ? b1 : b0;
      #pragma unroll
      for (int n = 0; n < 4; n++){
        int col = (int)colB + wn4 * 64 + n * 16 + lrow;
        float ba = bias[col];
        #pragma unroll
        for (int m = 0; m < 8; m++){
          long long r = rowA + wm2 * 128 + m * 16 + kgrp * 4;
          #pragma unroll
          for (int j = 0; j < 4; j++)
            c[(r + j) * ldc + col] = f2h(acc[m][n][j] + ba);
        }
      }
    } else {
      #pragma unroll
      for (int n = 0; n < 4; n++){
        int col = (int)colB + wn4 * 64 + n * 16 + lrow;
        float ba = b2[col];
        #pragma unroll
        for (int m = 0; m < 8; m++){
          long long r = rowA + wm2 * 128 + m * 16 + kgrp * 4;
          int bb = (int)(r >> 11);
          int s  = (int)(r & 2047);
          u16* vtc = Vt + ((long long)bb * HD + col) * SQ + s;
          #pragma unroll
          for (int j = 0; j < 4; j++){
            float v = acc[m][n][j] + ba;
            Cf[(r + j) * ldc + col] = v;
            vtc[j] = f2h(v);
          }
        }
      }
    }
  } else {
    float* cf = Cf + (long long)z * sC;
    #pragma unroll
    for (int n = 0; n < 4; n++){
      int col = (int)colB + wn4 * 64 + n * 16 + lrow;
      #pragma unroll
      for (int m = 0; m < 8; m++){
        long long r = rowA + wm2 * 128 + m * 16 + kgrp * 4;
        #pragma unroll
        for (int j = 0; j < 4; j++){
          long long o = (r + j) * ldc + col;
          cf[o] = acc[m][n][j] + cf[o];     // residual: read V then overwrite
        }
      }
    }
  }
}

// ---------------------------------------------------------------------------
// Scores GEMM: 128x256 f16 tiles, BK=64, 8 waves (2M x 4N), wave tile 64x64.
// Same pipeline/swizzle/dataflow as gemm8 (round-10 core). grid.x = 72
// triangular tiles per batch (strip i of 128 rows has floor(i/2)+1 col-tiles
// of 256). Output: compact f32, tile t at Cf + z*CE + t*32768, ld=256.
// Per-element K-accumulation order identical to the 256^2 version.
// ---------------------------------------------------------------------------
__global__ __launch_bounds__(512, 2)
void gemm_sc(const u16* __restrict__ A, const u16* __restrict__ B,
             float* Cf, long long sA, long long sB, long long sC)
{
  const int z = blockIdx.z;
  int t = blockIdx.x;
  int i = (int)(2.f * sqrtf((float)t));
  if (i > 15) i = 15;
  while (TB128(i + 1) <= t) ++i;
  while (TB128(i) > t) --i;
  const int bj = t - TB128(i);

  __shared__ short lds[2 * 24576];     // 2 bufs x (A 128x64 + B 256x64) f16

  const int tid  = threadIdx.x;
  const int lane = tid & 63, w = tid >> 6;
  const int wm2 = w >> 2, wn4 = w & 3;
  const int lrow = lane & 15, kgrp = lane >> 4;

  const long long rowA = (long long)i * 128;
  const long long colB = (long long)bj * 256;

  const int rt = tid >> 3;
  const int gs = (tid & 7) ^ (rt & 7);

  const u16 *sAp[2], *sBp[4];
  {
    const u16* Ab0 = A + (long long)z * sA;
    #pragma unroll
    for (int k = 0; k < 2; k++)
      sAp[k] = Ab0 + (rowA + k * 64 + rt) * (long long)HD + gs * 8;
    const u16* Bb = B + (long long)z * sB;
    #pragma unroll
    for (int k = 0; k < 4; k++)
      sBp[k] = Bb + (colB + k * 64 + rt) * (long long)HD + gs * 8;
  }

  #define ADST2(buf,k) (lds + (buf) * 24576 +        (k) * 4096 + w * 512)
  #define BDST2(buf,k) (lds + (buf) * 24576 + 8192 + (k) * 4096 + w * 512)

  const int fl = lrow & 7;
  const int swzk[2] = { ((0 + kgrp) ^ fl) * 8, ((4 + kgrp) ^ fl) * 8 };
  const int arow = (wm2 * 64 + lrow) * 64;          // + m*1024
  const int brow = 8192 + (wn4 * 64 + lrow) * 64;   // + n*1024

  f32x4 acc[4][4];
  const f32x4 zf = {0.f, 0.f, 0.f, 0.f};
  #pragma unroll
  for (int m = 0; m < 4; m++)
    #pragma unroll
    for (int n = 0; n < 4; n++) acc[m][n] = zf;

  const int KT = HD >> 6;

  auto advance = [&](){
    #pragma unroll
    for (int k = 0; k < 2; k++) sAp[k] += 64;
    #pragma unroll
    for (int k = 0; k < 4; k++) sBp[k] += 64;
  };

  #pragma unroll
  for (int k = 0; k < 2; k++) STG(sAp[k], ADST2(0, k));
  #pragma unroll
  for (int k = 0; k < 4; k++) STG(sBp[k], BDST2(0, k));
  advance();
  __syncthreads();

  int cur = 0;
  for (int kt = 0; kt < KT; ++kt){
    const bool pf = (kt + 1 < KT);
    const short* Ab = lds + cur * 24576;
    const int nb = cur ^ 1;

    if (pf){
      #pragma unroll
      for (int k = 0; k < 2; k++) STG(sAp[k], ADST2(nb, k));
      #pragma unroll
      for (int k = 0; k < 4; k++) STG(sBp[k], BDST2(nb, k));
      advance();
    }

    f16x8 bq[4][2], aq[4][2];
    #pragma unroll
    for (int n = 0; n < 4; n++)
      #pragma unroll
      for (int ks = 0; ks < 2; ks++)
        bq[n][ks] = *(const f16x8*)(Ab + brow + n * 1024 + swzk[ks]);
    #pragma unroll
    for (int m = 0; m < 4; m++)
      #pragma unroll
      for (int ks = 0; ks < 2; ks++)
        aq[m][ks] = *(const f16x8*)(Ab + arow + m * 1024 + swzk[ks]);

    __builtin_amdgcn_s_setprio(1);
    #pragma unroll
    for (int ks = 0; ks < 2; ks++)
      #pragma unroll
      for (int n = 0; n < 4; n++)
        #pragma unroll
        for (int m = 0; m < 4; m++)
          acc[m][n] = __builtin_amdgcn_mfma_f32_16x16x32_f16(aq[m][ks], bq[n][ks],
                                                             acc[m][n], 0, 0, 0);
    __builtin_amdgcn_s_setprio(0);

    __syncthreads();
    cur ^= 1;
  }
  #undef ADST2
  #undef BDST2

  // compact 128x256 tile store, ld=256 (f32)
  float* cf = Cf + (long long)z * sC + (long long)t * 32768;
  #pragma unroll
  for (int n = 0; n < 4; n++){
    int col = wn4 * 64 + n * 16 + lrow;
    #pragma unroll
    for (int m = 0; m < 4; m++){
      int r = wm2 * 64 + m * 16 + kgrp * 4;
      #pragma unroll
      for (int j = 0; j < 4; j++)
        cf[(r + j) * 256 + col] = acc[m][n][j];
    }
  }
}

// x fp32 -> f16 plane
__global__ __launch_bounds__(256)
void prep_x(const float* __restrict__ X, u16* __restrict__ Xh)
{
  const long long n8 = (long long)NTOT * HD / 8;
  for (long long i = (long long)blockIdx.x * 256 + threadIdx.x; i < n8;
       i += (long long)gridDim.x * 256){
    const float* p = X + i * 8;
    float4 a = *(const float4*)p;
    float4 b = *(const float4*)(p + 4);
    float f[8] = {a.x, a.y, a.z, a.w, b.x, b.y, b.z, b.w};
    s16x8 h;
    #pragma unroll
    for (int j = 0; j < 8; j++) h[j] = (short)f2h(f[j]);
    *(s16x8*)&Xh[i * 8] = h;
  }
}

// W[k][n] -> transposed f16 Wt[z][n][k]
__global__ void prep_w(const float* __restrict__ Wq, const float* __restrict__ Wk,
                       const float* __restrict__ Wv, u16* __restrict__ Wt)
{
  __shared__ float t[32][33];
  const float* Win = (blockIdx.z == 0) ? Wq : (blockIdx.z == 1) ? Wk : Wv;
  const size_t zo = (size_t)blockIdx.z * HD * HD;
  int n0 = blockIdx.x * 32, k0 = blockIdx.y * 32;
  int tx = threadIdx.x, ty = threadIdx.y;
  #pragma unroll
  for (int i = 0; i < 4; i++)
    t[ty + 8*i][tx] = Win[(size_t)(k0 + ty + 8*i) * HD + n0 + tx];
  __syncthreads();
  #pragma unroll
  for (int i = 0; i < 4; i++)
    Wt[zo + (size_t)(n0 + ty + 8*i) * HD + k0 + tx] = f2h(t[tx][ty + 8*i]);
}

// softmax over compact 128x256 SC strips; writes f16 probs IN-PLACE into the
// first 512B of each (tile,row)'s own 1KB f32 row span (row self-owned).
__global__ __launch_bounds__(256)
void softmax_causal(const float* __restrict__ SC, u16* __restrict__ P)
{
  const int s = blockIdx.x;
  const int ti = s >> 7;                // 128-row strip
  const int tb = TB128(ti);
  const float* scb = SC + (long long)blockIdx.y * CE + (long long)tb * 32768
                   + (long long)(s & 127) * 256;
  u16* pb = P + (long long)blockIdx.y * (2 * CE) + (long long)tb * 65536
          + (long long)(s & 127) * 512;

  __shared__ float buf[SQ];
  __shared__ float red[4];
  const int tid = threadIdx.x, lane = tid & 63, wid = tid >> 6;

  float m = -3.4e38f;
  for (int t = tid; t <= s; t += 256){
    float v = scb[(t >> 8) * 32768 + (t & 255)];
    buf[t] = v; m = fmaxf(m, v);
  }
  #pragma unroll
  for (int o = 32; o; o >>= 1) m = fmaxf(m, __shfl_xor(m, o));
  if (lane == 0) red[wid] = m;
  __syncthreads();
  m = fmaxf(fmaxf(red[0], red[1]), fmaxf(red[2], red[3]));
  __syncthreads();

  float sum = 0.f;
  for (int t = tid; t <= s; t += 256){ float e = __expf(buf[t] - m); buf[t] = e; sum += e; }
  #pragma unroll
  for (int o = 32; o; o >>= 1) sum += __shfl_xor(sum, o);
  if (lane == 0) red[wid] = sum;
  __syncthreads();
  sum = red[0] + red[1] + red[2] + red[3];
  const float inv = 1.f / sum;

  const int lim = ((ti >> 1) + 1) << 8;   // strip has floor(ti/2)+1 col tiles
  for (int t = tid; t < lim; t += 256)
    pb[(t >> 8) * 65536 + (t & 255)] = (t <= s) ? f2h(buf[t] * inv) : (u16)0;
}

__global__ __launch_bounds__(256)
void layernorm_inplace(float* __restrict__ Y, const float* __restrict__ gamma,
                       const float* __restrict__ beta)
{
  float* y = Y + (long long)blockIdx.x * HD;
  const int tid = threadIdx.x, lane = tid & 63, wid = tid >> 6;
  float xv[4];
  float s = 0.f, ss = 0.f;
  #pragma unroll
  for (int i = 0; i < 4; i++){
    float v = y[tid + i * 256];
    xv[i] = v; s += v; ss += v * v;
  }
  #pragma unroll
  for (int o = 32; o; o >>= 1){ s += __shfl_xor(s, o); ss += __shfl_xor(ss, o); }
  __shared__ float r1[4], r2[4];
  if (lane == 0){ r1[wid] = s; r2[wid] = ss; }
  __syncthreads();
  s  = r1[0] + r1[1] + r1[2] + r1[3];
  ss = r2[0] + r2[1] + r2[2] + r2[3];
  const float mu   = s * (1.f / HD);
  const float var  = ss * (1.f / HD) - mu * mu;
  const float rstd = rsqrtf(var + 1e-5f);
  #pragma unroll
  for (int i = 0; i < 4; i++){
    int c = tid + i * 256;
    y[c] = (xv[i] - mu) * rstd * gamma[c] + beta[c];
  }
}

extern "C" void kernel_launch(void* const* d_in, const int* in_sizes, int n_in,
                              void* d_out, int out_size, void* d_ws, size_t ws_size,
                              hipStream_t stream)
{
  const float* x     = (const float*)d_in[0];
  const float* Wq    = (const float*)d_in[1];
  const float* bq    = (const float*)d_in[2];
  const float* Wk    = (const float*)d_in[3];
  const float* bk    = (const float*)d_in[4];
  const float* Wv    = (const float*)d_in[5];
  const float* bv    = (const float*)d_in[6];
  const float* gamma = (const float*)d_in[7];
  const float* beta  = (const float*)d_in[8];
  float* out = (float*)d_out;

  char* wsp = (char*)d_ws;
  size_t off = 0;
  auto alloc = [&](size_t bytes) -> char* {
    char* p = wsp + off;
    off = (off + bytes + 255) & ~(size_t)255;
    return p;
  };

  u16* Wt = (u16*)alloc(3ULL * HD * HD * 2);          // 6.3 MB  (transposed f16)
  u16* QK = (u16*)alloc(2ULL * NTOT * HD * 2);        // 67.1 MB (Q plane, K plane)
  u16* Vt = (u16*)alloc((size_t)NB * HD * SQ * 2);    // 33.6 MB (V transposed f16)

  // region: xh (phase A) aliased with compact SC (phase B; P lives inside SC)
  size_t rem = (ws_size > off) ? (ws_size - off) : 0;
  size_t perb = (size_t)CE * 4;                       // 9.4 MB per batch
  int G = (int)(rem / perb);
  if (G > NB) G = NB;
  if (G < 1)  G = 1;
  u16*   xh = (u16*)(wsp + off);                      // 33.5 MB
  float* SC = (float*)(wsp + off);                    // G * 9.4 MB (compact, P in-place)

  u16* Qh = QK;
  u16* Kh = QK + (size_t)NTOT * HD;
  float* V = out;   // V fp32 lives in d_out; PV reads V[o] then overwrites o

  prep_x<<<dim3(2048), dim3(256), 0, stream>>>(x, xh);
  prep_w<<<dim3(HD/32, HD/32, 3), dim3(32, 8), 0, stream>>>(Wq, Wk, Wv, Wt);

  // QKV projection: z=0 -> Q f16, z=1 -> K f16, z=2 -> V fp32(d_out) + Vt f16
  gemm8<0><<<dim3(NTOT/256, HD/256, 3), 512, 0, stream>>>(
      xh, Wt, V, QK, Vt, bq, bk, bv,
      HD, HD, HD, HD,
      0LL, (long long)HD * HD, (long long)NTOT * HD);

  for (int g0 = 0; g0 < NB; g0 += G){
    int g = (G < NB - g0) ? G : (NB - g0);
    // scores: 72 triangular 128x256 tiles per batch (576 blocks at G=8)
    gemm_sc<<<dim3(72, 1, g), 512, 0, stream>>>(
        Qh + (size_t)g0 * SQ * HD, Kh + (size_t)g0 * SQ * HD, SC,
        (long long)SQ * HD, (long long)SQ * HD, CE);
    softmax_causal<<<dim3(SQ, g), 256, 0, stream>>>(SC, (u16*)SC);
    // PV + residual; A = in-place compact P (u16 view of SC region)
    gemm8<2><<<dim3(NT2, HD/256, g), 512, 0, stream>>>(
        (const u16*)SC, Vt + (size_t)g0 * HD * SQ,
        out + (size_t)g0 * SQ * HD, nullptr, nullptr, nullptr, nullptr, nullptr,
        SQ, 512, SQ, HD,
        2 * CE, (long long)HD * SQ, (long long)SQ * HD);
  }

  layernorm_inplace<<<dim3(NTOT), 256, 0, stream>>>(out, gamma, beta);
}